// Round 1
// baseline (1414.389 us; speedup 1.0000x reference)
//
#include <hip/hip_runtime.h>
#include <hip/hip_bf16.h>
#include <stdint.h>

#define S_TOK 8192
#define H_DIM 2048
#define I_DIM 2048
#define E_NUM 8

typedef __attribute__((ext_vector_type(4))) float f32x4;
typedef __attribute__((ext_vector_type(8))) short bf16x8;

// f32 -> bf16 RNE
__device__ __forceinline__ unsigned short f2bf(float f) {
    unsigned int u = __float_as_uint(f);
    unsigned int r = (u + 0x7FFFu + ((u >> 16) & 1u)) >> 16;
    return (unsigned short)r;
}

// async global->LDS, 16B per lane. LDS dest is wave-uniform base + lane*16.
__device__ __forceinline__ void async_copy16(void* lds, const void* g) {
    __builtin_amdgcn_global_load_lds(
        (const __attribute__((address_space(1))) void*)(uintptr_t)g,
        (__attribute__((address_space(3))) void*)(uintptr_t)lds,
        16, 0, 0);
}

// ---------------- f32 -> bf16 conversion ----------------
__global__ void cvt_kernel(const float* __restrict__ src, unsigned short* __restrict__ dst, long n) {
    long i0 = ((long)blockIdx.x * blockDim.x + threadIdx.x) * 4;
    long stride = (long)gridDim.x * blockDim.x * 4;
    for (long i = i0; i < n; i += stride) {
        float4 v = *(const float4*)(src + i);
        ushort4 o;
        o.x = f2bf(v.x); o.y = f2bf(v.y); o.z = f2bf(v.z); o.w = f2bf(v.w);
        *(ushort4*)(dst + i) = o;
    }
}

// ---------------- router: logits (f32 exact), top-2, expert lists ----------------
__global__ void router_kernel(const float* __restrict__ hs, const float* __restrict__ wg,
                              float* __restrict__ logits, int* __restrict__ cnt,
                              int* __restrict__ tok_of, float* __restrict__ wgt_of) {
    int t = blockIdx.x;
    int tid = threadIdx.x;
    const float* hrow = hs + (size_t)t * H_DIM;
    float4 h0 = *(const float4*)(hrow + tid * 8);
    float4 h1 = *(const float4*)(hrow + tid * 8 + 4);
    float p[E_NUM];
#pragma unroll
    for (int e = 0; e < E_NUM; ++e) {
        const float* w = wg + (size_t)e * H_DIM + tid * 8;
        float4 w0 = *(const float4*)(w);
        float4 w1v = *(const float4*)(w + 4);
        p[e] = h0.x * w0.x + h0.y * w0.y + h0.z * w0.z + h0.w * w0.w +
               h1.x * w1v.x + h1.y * w1v.y + h1.z * w1v.z + h1.w * w1v.w;
    }
#pragma unroll
    for (int e = 0; e < E_NUM; ++e)
#pragma unroll
        for (int d = 32; d > 0; d >>= 1) p[e] += __shfl_xor(p[e], d, 64);

    __shared__ float red[4][E_NUM];
    int wave = tid >> 6, lane = tid & 63;
    if (lane == 0) {
#pragma unroll
        for (int e = 0; e < E_NUM; ++e) red[wave][e] = p[e];
    }
    __syncthreads();
    if (tid == 0) {
        float l[E_NUM];
#pragma unroll
        for (int e = 0; e < E_NUM; ++e) l[e] = red[0][e] + red[1][e] + red[2][e] + red[3][e];
#pragma unroll
        for (int e = 0; e < E_NUM; ++e) logits[(size_t)t * E_NUM + e] = l[e];
        int i1 = 0;
#pragma unroll
        for (int e = 1; e < E_NUM; ++e) if (l[e] > l[i1]) i1 = e;
        int i2 = (i1 == 0) ? 1 : 0;
#pragma unroll
        for (int e = 0; e < E_NUM; ++e) if (e != i1 && l[e] > l[i2]) i2 = e;
        // normalized top-2 softmax weights: 1/(1+exp(l2-l1))
        float b = __expf(l[i2] - l[i1]);
        float wA = 1.0f / (1.0f + b);
        float wB = 1.0f - wA;
        int s1 = atomicAdd(&cnt[i1], 1);
        tok_of[i1 * S_TOK + s1] = t; wgt_of[i1 * S_TOK + s1] = wA;
        int s2 = atomicAdd(&cnt[i2], 1);
        tok_of[i2 * S_TOK + s2] = t; wgt_of[i2 * S_TOK + s2] = wB;
    }
}

__global__ void offsets_kernel(const int* __restrict__ cnt, int* __restrict__ off) {
    if (threadIdx.x == 0) {
        int s = 0;
        for (int e = 0; e < E_NUM; ++e) { off[e] = s; s += cnt[e]; }
    }
}

// ---------------- GEMM1: gathered hidden x w1[e]^T, fused silu*up*wgt -> h ----------------
// block tile: 128 rows x 128 B-rows (64 gate cols + 64 up cols), BK=64, 4 waves (4x1 on M).
__global__ __launch_bounds__(256) void gemm1_kernel(
    const unsigned short* __restrict__ hsb, const unsigned short* __restrict__ w1b,
    const int* __restrict__ cnt, const int* __restrict__ off,
    const int* __restrict__ tok_of, const float* __restrict__ wgt_of,
    unsigned short* __restrict__ hbuf) {
    const int MT = S_TOK / 128;  // 64
    const int NT = I_DIM / 64;   // 32
    int bx = blockIdx.x;
    int e = bx / (MT * NT);
    int r = bx % (MT * NT);
    int mt = r % MT;
    int nt = r / MT;
    int C = cnt[e];
    if (mt * 128 >= C) return;
    int O = off[e];

    __shared__ __align__(16) unsigned short As[128 * 64];
    __shared__ __align__(16) unsigned short Bs[128 * 64];

    int tid = threadIdx.x;
    int wave = tid >> 6, lane = tid & 63;

    // staging source pointers. LDS unit u holds logical 16B-col cu = (u&7)^(row&7)
    const char* aptr[4];
    const char* bptr[4];
#pragma unroll
    for (int i = 0; i < 4; ++i) {
        int u = (wave * 4 + i) * 64 + lane;
        int row = u >> 3;
        int cu = (u & 7) ^ (row & 7);
        int grow = mt * 128 + row; if (grow > C - 1) grow = C - 1;
        int token = tok_of[e * S_TOK + grow];
        aptr[i] = (const char*)(hsb + (size_t)token * H_DIM + cu * 8);
        int brow = (row < 64) ? (nt * 64 + row) : (I_DIM + nt * 64 + (row - 64));
        bptr[i] = (const char*)(w1b + (size_t)e * (2 * I_DIM) * H_DIM + (size_t)brow * H_DIM + cu * 8);
    }

    // swizzled ds_read byte offsets
    int aoff[2][2], boff[8][2];
#pragma unroll
    for (int m = 0; m < 2; ++m)
#pragma unroll
        for (int ks = 0; ks < 2; ++ks) {
            int row = wave * 32 + m * 16 + (lane & 15);
            int cu = ks * 4 + (lane >> 4);
            aoff[m][ks] = row * 128 + ((cu ^ (row & 7)) * 16);
        }
#pragma unroll
    for (int n = 0; n < 8; ++n)
#pragma unroll
        for (int ks = 0; ks < 2; ++ks) {
            int row = n * 16 + (lane & 15);
            int cu = ks * 4 + (lane >> 4);
            boff[n][ks] = row * 128 + ((cu ^ (row & 7)) * 16);
        }

    f32x4 acc[2][8];
#pragma unroll
    for (int m = 0; m < 2; ++m)
#pragma unroll
        for (int n = 0; n < 8; ++n)
#pragma unroll
            for (int q = 0; q < 4; ++q) acc[m][n][q] = 0.0f;

    char* abase = (char*)As;
    char* bbase = (char*)Bs;

    for (int kt = 0; kt < H_DIM / 64; ++kt) {
#pragma unroll
        for (int i = 0; i < 4; ++i)
            async_copy16(abase + (wave * 4 + i) * 1024, aptr[i] + kt * 128);
#pragma unroll
        for (int i = 0; i < 4; ++i)
            async_copy16(bbase + (wave * 4 + i) * 1024, bptr[i] + kt * 128);
        asm volatile("s_waitcnt vmcnt(0)" ::: "memory");
        __syncthreads();

#pragma unroll
        for (int ks = 0; ks < 2; ++ks) {
            bf16x8 a0 = *(const bf16x8*)(abase + aoff[0][ks]);
            bf16x8 a1 = *(const bf16x8*)(abase + aoff[1][ks]);
#pragma unroll
            for (int n = 0; n < 8; ++n) {
                bf16x8 bf = *(const bf16x8*)(bbase + boff[n][ks]);
                acc[0][n] = __builtin_amdgcn_mfma_f32_16x16x32_bf16(a0, bf, acc[0][n], 0, 0, 0);
                acc[1][n] = __builtin_amdgcn_mfma_f32_16x16x32_bf16(a1, bf, acc[1][n], 0, 0, 0);
            }
        }
        __syncthreads();
    }

    // epilogue: h = silu(gate)*up*wgt, frag n pairs with n+4 (same lane/col)
#pragma unroll
    for (int m = 0; m < 2; ++m)
#pragma unroll
        for (int rr = 0; rr < 4; ++rr) {
            int row = mt * 128 + wave * 32 + m * 16 + (lane >> 4) * 4 + rr;
            if (row < C) {
                float wgt = wgt_of[e * S_TOK + row];
                unsigned short* hp = hbuf + (size_t)(O + row) * I_DIM + nt * 64 + (lane & 15);
#pragma unroll
                for (int n = 0; n < 4; ++n) {
                    float g = acc[m][n][rr];
                    float u = acc[m][n + 4][rr];
                    float hv = (g / (1.0f + __expf(-g))) * u * wgt;
                    hp[n * 16] = f2bf(hv);
                }
            }
        }
}

// ---------------- GEMM2: h x w2[e]^T, scatter-add into out ----------------
__global__ __launch_bounds__(256) void gemm2_kernel(
    const unsigned short* __restrict__ hbuf, const unsigned short* __restrict__ w2b,
    const int* __restrict__ cnt, const int* __restrict__ off,
    const int* __restrict__ tok_of, float* __restrict__ out) {
    const int MT = S_TOK / 128;  // 64
    const int NT = H_DIM / 128;  // 16
    int bx = blockIdx.x;
    int e = bx / (MT * NT);
    int r = bx % (MT * NT);
    int mt = r % MT;
    int nt = r / MT;
    int C = cnt[e];
    if (mt * 128 >= C) return;
    int O = off[e];

    __shared__ __align__(16) unsigned short As[128 * 64];
    __shared__ __align__(16) unsigned short Bs[128 * 64];

    int tid = threadIdx.x;
    int wave = tid >> 6, lane = tid & 63;

    const char* aptr[4];
    const char* bptr[4];
#pragma unroll
    for (int i = 0; i < 4; ++i) {
        int u = (wave * 4 + i) * 64 + lane;
        int row = u >> 3;
        int cu = (u & 7) ^ (row & 7);
        int grow = mt * 128 + row; if (grow > C - 1) grow = C - 1;
        aptr[i] = (const char*)(hbuf + (size_t)(O + grow) * I_DIM + cu * 8);
        int brow = nt * 128 + row;
        bptr[i] = (const char*)(w2b + (size_t)e * H_DIM * I_DIM + (size_t)brow * I_DIM + cu * 8);
    }

    int aoff[2][2], boff[8][2];
#pragma unroll
    for (int m = 0; m < 2; ++m)
#pragma unroll
        for (int ks = 0; ks < 2; ++ks) {
            int row = wave * 32 + m * 16 + (lane & 15);
            int cu = ks * 4 + (lane >> 4);
            aoff[m][ks] = row * 128 + ((cu ^ (row & 7)) * 16);
        }
#pragma unroll
    for (int n = 0; n < 8; ++n)
#pragma unroll
        for (int ks = 0; ks < 2; ++ks) {
            int row = n * 16 + (lane & 15);
            int cu = ks * 4 + (lane >> 4);
            boff[n][ks] = row * 128 + ((cu ^ (row & 7)) * 16);
        }

    f32x4 acc[2][8];
#pragma unroll
    for (int m = 0; m < 2; ++m)
#pragma unroll
        for (int n = 0; n < 8; ++n)
#pragma unroll
            for (int q = 0; q < 4; ++q) acc[m][n][q] = 0.0f;

    char* abase = (char*)As;
    char* bbase = (char*)Bs;

    for (int kt = 0; kt < I_DIM / 64; ++kt) {
#pragma unroll
        for (int i = 0; i < 4; ++i)
            async_copy16(abase + (wave * 4 + i) * 1024, aptr[i] + kt * 128);
#pragma unroll
        for (int i = 0; i < 4; ++i)
            async_copy16(bbase + (wave * 4 + i) * 1024, bptr[i] + kt * 128);
        asm volatile("s_waitcnt vmcnt(0)" ::: "memory");
        __syncthreads();

#pragma unroll
        for (int ks = 0; ks < 2; ++ks) {
            bf16x8 a0 = *(const bf16x8*)(abase + aoff[0][ks]);
            bf16x8 a1 = *(const bf16x8*)(abase + aoff[1][ks]);
#pragma unroll
            for (int n = 0; n < 8; ++n) {
                bf16x8 bf = *(const bf16x8*)(bbase + boff[n][ks]);
                acc[0][n] = __builtin_amdgcn_mfma_f32_16x16x32_bf16(a0, bf, acc[0][n], 0, 0, 0);
                acc[1][n] = __builtin_amdgcn_mfma_f32_16x16x32_bf16(a1, bf, acc[1][n], 0, 0, 0);
            }
        }
        __syncthreads();
    }

#pragma unroll
    for (int m = 0; m < 2; ++m)
#pragma unroll
        for (int rr = 0; rr < 4; ++rr) {
            int row = mt * 128 + wave * 32 + m * 16 + (lane >> 4) * 4 + rr;
            if (row < C) {
                int token = tok_of[e * S_TOK + row];
                float* op = out + (size_t)token * H_DIM + nt * 128 + (lane & 15);
#pragma unroll
                for (int n = 0; n < 8; ++n)
                    unsafeAtomicAdd(op + n * 16, acc[m][n][rr]);
            }
        }
}

extern "C" void kernel_launch(void* const* d_in, const int* in_sizes, int n_in,
                              void* d_out, int out_size, void* d_ws, size_t ws_size,
                              hipStream_t stream) {
    const float* hs = (const float*)d_in[0];
    const float* wg = (const float*)d_in[1];
    const float* w1 = (const float*)d_in[2];
    const float* w2 = (const float*)d_in[3];
    // d_in[4] = top_k (always 2 for this problem)

    float* out = (float*)d_out;
    float* logits = out + (size_t)S_TOK * H_DIM;

    char* ws = (char*)d_ws;
    int* cnt = (int*)ws;                       // 32 B
    int* off = (int*)(ws + 256);               // 32 B
    int* tok_of = (int*)(ws + 512);            // E*S ints
    float* wgt_of = (float*)(ws + 512 + (size_t)E_NUM * S_TOK * 4);
    size_t o = 512 + (size_t)E_NUM * S_TOK * 8;
    o = (o + 4095) & ~(size_t)4095;
    unsigned short* hsb = (unsigned short*)(ws + o);  o += (size_t)S_TOK * H_DIM * 2;          // 32 MiB
    unsigned short* wxb = (unsigned short*)(ws + o);  o += (size_t)E_NUM * 2 * I_DIM * H_DIM * 2; // 128 MiB (w1, reused for w2)
    unsigned short* hbuf = (unsigned short*)(ws + o); o += (size_t)S_TOK * 2 * I_DIM * 2;      // 64 MiB
    // total ~225 MiB

    hipMemsetAsync(out, 0, (size_t)S_TOK * H_DIM * sizeof(float), stream);
    hipMemsetAsync(cnt, 0, 64, stream);

    cvt_kernel<<<4096, 256, 0, stream>>>(hs, hsb, (long)S_TOK * H_DIM);
    cvt_kernel<<<4096, 256, 0, stream>>>(w1, wxb, (long)E_NUM * 2 * I_DIM * H_DIM);
    router_kernel<<<S_TOK, 256, 0, stream>>>(hs, wg, logits, cnt, tok_of, wgt_of);
    offsets_kernel<<<1, 64, 0, stream>>>(cnt, off);
    gemm1_kernel<<<E_NUM * 64 * 32, 256, 0, stream>>>(hsb, wxb, cnt, off, tok_of, wgt_of, hbuf);
    cvt_kernel<<<4096, 256, 0, stream>>>(w2, wxb, (long)E_NUM * H_DIM * I_DIM);
    gemm2_kernel<<<E_NUM * 64 * 16, 256, 0, stream>>>(hbuf, wxb, cnt, off, tok_of, out);
}

// Round 2
// 940.042 us; speedup vs baseline: 1.5046x; 1.5046x over previous
//
#include <hip/hip_runtime.h>
#include <hip/hip_bf16.h>
#include <stdint.h>

#define S_TOK 8192
#define H_DIM 2048
#define I_DIM 2048
#define E_NUM 8

typedef __attribute__((ext_vector_type(4))) float f32x4;
typedef __attribute__((ext_vector_type(8))) short bf16x8;

// f32 -> bf16 RNE
__device__ __forceinline__ unsigned short f2bf(float f) {
    unsigned int u = __float_as_uint(f);
    unsigned int r = (u + 0x7FFFu + ((u >> 16) & 1u)) >> 16;
    return (unsigned short)r;
}

// async global->LDS, 16B per lane. LDS dest is wave-uniform base + lane*16.
__device__ __forceinline__ void async_copy16(void* lds, const void* g) {
    __builtin_amdgcn_global_load_lds(
        (const __attribute__((address_space(1))) void*)(uintptr_t)g,
        (__attribute__((address_space(3))) void*)(uintptr_t)lds,
        16, 0, 0);
}

// XCD-aware block swizzle (grid % 8 == 0 for all our grids)
__device__ __forceinline__ int xcd_swizzle(int bid, int nwg) {
    int cpx = nwg >> 3;
    return (bid & 7) * cpx + (bid >> 3);
}

// ---------------- f32 -> bf16 conversion ----------------
__global__ void cvt_kernel(const float* __restrict__ src, unsigned short* __restrict__ dst, long n) {
    long i0 = ((long)blockIdx.x * blockDim.x + threadIdx.x) * 4;
    long stride = (long)gridDim.x * blockDim.x * 4;
    for (long i = i0; i < n; i += stride) {
        float4 v = *(const float4*)(src + i);
        ushort4 o;
        o.x = f2bf(v.x); o.y = f2bf(v.y); o.z = f2bf(v.z); o.w = f2bf(v.w);
        *(ushort4*)(dst + i) = o;
    }
}

// ---------------- router: logits (f32 exact), top-2, expert lists ----------------
__global__ void router_kernel(const float* __restrict__ hs, const float* __restrict__ wg,
                              float* __restrict__ logits, int* __restrict__ cnt,
                              int* __restrict__ tok_of, float* __restrict__ wgt_of) {
    int t = blockIdx.x;
    int tid = threadIdx.x;
    const float* hrow = hs + (size_t)t * H_DIM;
    float4 h0 = *(const float4*)(hrow + tid * 8);
    float4 h1 = *(const float4*)(hrow + tid * 8 + 4);
    float p[E_NUM];
#pragma unroll
    for (int e = 0; e < E_NUM; ++e) {
        const float* w = wg + (size_t)e * H_DIM + tid * 8;
        float4 w0 = *(const float4*)(w);
        float4 w1v = *(const float4*)(w + 4);
        p[e] = h0.x * w0.x + h0.y * w0.y + h0.z * w0.z + h0.w * w0.w +
               h1.x * w1v.x + h1.y * w1v.y + h1.z * w1v.z + h1.w * w1v.w;
    }
#pragma unroll
    for (int e = 0; e < E_NUM; ++e)
#pragma unroll
        for (int d = 32; d > 0; d >>= 1) p[e] += __shfl_xor(p[e], d, 64);

    __shared__ float red[4][E_NUM];
    int wave = tid >> 6, lane = tid & 63;
    if (lane == 0) {
#pragma unroll
        for (int e = 0; e < E_NUM; ++e) red[wave][e] = p[e];
    }
    __syncthreads();
    if (tid == 0) {
        float l[E_NUM];
#pragma unroll
        for (int e = 0; e < E_NUM; ++e) l[e] = red[0][e] + red[1][e] + red[2][e] + red[3][e];
#pragma unroll
        for (int e = 0; e < E_NUM; ++e) logits[(size_t)t * E_NUM + e] = l[e];
        int i1 = 0;
#pragma unroll
        for (int e = 1; e < E_NUM; ++e) if (l[e] > l[i1]) i1 = e;
        int i2 = (i1 == 0) ? 1 : 0;
#pragma unroll
        for (int e = 0; e < E_NUM; ++e) if (e != i1 && l[e] > l[i2]) i2 = e;
        float b = __expf(l[i2] - l[i1]);
        float wA = 1.0f / (1.0f + b);
        float wB = 1.0f - wA;
        int s1 = atomicAdd(&cnt[i1], 1);
        tok_of[i1 * S_TOK + s1] = t; wgt_of[i1 * S_TOK + s1] = wA;
        int s2 = atomicAdd(&cnt[i2], 1);
        tok_of[i2 * S_TOK + s2] = t; wgt_of[i2 * S_TOK + s2] = wB;
    }
}

__global__ void offsets_kernel(const int* __restrict__ cnt, int* __restrict__ off) {
    if (threadIdx.x == 0) {
        int s = 0;
        for (int e = 0; e < E_NUM; ++e) { off[e] = s; s += cnt[e]; }
    }
}

// ---------------- GEMM1: gathered hidden x w1[e]^T, fused silu*up*wgt -> h ----------------
// tile: 128 rows x 128 B-rows, B-rows interleaved [g0-31|u0-31|g32-63|u32-63]
// waves 2x2; each wave acc[4][4]; 2-phase double-buffered pipeline.
__global__ __launch_bounds__(256) void gemm1_kernel(
    const unsigned short* __restrict__ hsb, const unsigned short* __restrict__ w1b,
    const int* __restrict__ cnt, const int* __restrict__ off,
    const int* __restrict__ tok_of, const float* __restrict__ wgt_of,
    unsigned short* __restrict__ hbuf) {
    const int MT = S_TOK / 128;  // 64
    const int NT = I_DIM / 64;   // 32  (64 h-cols per block)
    int bx = xcd_swizzle(blockIdx.x, E_NUM * MT * NT);
    int e = bx / (MT * NT);
    int r = bx % (MT * NT);
    int mt = r % MT;           // mt fast: consecutive work shares B-panel
    int nt = r / MT;
    int C = cnt[e];
    if (mt * 128 >= C) return;
    int O = off[e];

    __shared__ __align__(16) char lds[2][32768];  // per buf: A 16KB | B 16KB

    int tid = threadIdx.x;
    int wave = tid >> 6, lane = tid & 63;
    int wr = wave >> 1, wc = wave & 1;

    // staging source pointers (pre-swizzled per rule #21)
    const char* aptr[4];
    const char* bptr[4];
#pragma unroll
    for (int i = 0; i < 4; ++i) {
        int u = (wave * 4 + i) * 64 + lane;
        int row = u >> 3;
        int cu = (u & 7) ^ (row & 7);
        int grow = mt * 128 + row; if (grow > C - 1) grow = C - 1;
        int token = tok_of[e * S_TOK + grow];
        aptr[i] = (const char*)(hsb + (size_t)token * H_DIM + cu * 8);
        // interleaved B-row mapping: group = row>>5 (0:g lo,1:u lo,2:g hi,3:u hi)
        int group = row >> 5, within = row & 31;
        int base = nt * 64 + (group >> 1) * 32 + within;
        int brow = base + ((group & 1) ? I_DIM : 0);
        bptr[i] = (const char*)(w1b + (size_t)e * (2 * I_DIM) * H_DIM + (size_t)brow * H_DIM + cu * 8);
    }

    // swizzled ds_read byte offsets (relative to buffer base)
    int aoff[4][2], boff[4][2];
#pragma unroll
    for (int m = 0; m < 4; ++m)
#pragma unroll
        for (int ks = 0; ks < 2; ++ks) {
            int row = wr * 64 + m * 16 + (lane & 15);
            int cu = ks * 4 + (lane >> 4);
            aoff[m][ks] = row * 128 + ((cu ^ (row & 7)) * 16);
            int brw = wc * 64 + m * 16 + (lane & 15);
            boff[m][ks] = 16384 + brw * 128 + ((cu ^ (brw & 7)) * 16);
        }

    f32x4 acc[4][4];
#pragma unroll
    for (int m = 0; m < 4; ++m)
#pragma unroll
        for (int n = 0; n < 4; ++n)
#pragma unroll
            for (int q = 0; q < 4; ++q) acc[m][n][q] = 0.0f;

    auto stage = [&](int buf, int kt) {
#pragma unroll
        for (int i = 0; i < 4; ++i)
            async_copy16(lds[buf] + (wave * 4 + i) * 1024, aptr[i] + kt * 128);
#pragma unroll
        for (int i = 0; i < 4; ++i)
            async_copy16(lds[buf] + 16384 + (wave * 4 + i) * 1024, bptr[i] + kt * 128);
    };
    auto compute = [&](int buf) {
#pragma unroll
        for (int ks = 0; ks < 2; ++ks) {
            bf16x8 a[4], b[4];
#pragma unroll
            for (int m = 0; m < 4; ++m) a[m] = *(const bf16x8*)(lds[buf] + aoff[m][ks]);
#pragma unroll
            for (int n = 0; n < 4; ++n) b[n] = *(const bf16x8*)(lds[buf] + boff[n][ks]);
#pragma unroll
            for (int m = 0; m < 4; ++m)
#pragma unroll
                for (int n = 0; n < 4; ++n)
                    acc[m][n] = __builtin_amdgcn_mfma_f32_16x16x32_bf16(a[m], b[n], acc[m][n], 0, 0, 0);
        }
    };

    stage(0, 0);
    __syncthreads();  // drains vmcnt(0)
    int cur = 0;
    for (int kt = 0; kt < H_DIM / 64 - 1; ++kt) {
        stage(cur ^ 1, kt + 1);          // prefetch next tile
        asm volatile("" ::: "memory");   // keep issue before compute
        compute(cur);
        __syncthreads();                 // drains prefetch + compute reads
        cur ^= 1;
    }
    compute(cur);

    // epilogue: gate frag n in {0,1} pairs with up frag n+2 (same lane/col)
#pragma unroll
    for (int m = 0; m < 4; ++m)
#pragma unroll
        for (int q = 0; q < 4; ++q) {
            int row = mt * 128 + wr * 64 + m * 16 + (lane >> 4) * 4 + q;
            if (row < C) {
                float wgt = wgt_of[e * S_TOK + row];
                unsigned short* hp = hbuf + (size_t)(O + row) * I_DIM + nt * 64 + wc * 32 + (lane & 15);
#pragma unroll
                for (int n = 0; n < 2; ++n) {
                    float g = acc[m][n][q];
                    float u = acc[m][n + 2][q];
                    float hv = (g / (1.0f + __expf(-g))) * u * wgt;
                    hp[n * 16] = f2bf(hv);
                }
            }
        }
}

// ---------------- GEMM2: h x w2[e]^T, scatter-add into out ----------------
// tile 128x128, waves 2x2, acc[4][4], 2-phase pipeline.
__global__ __launch_bounds__(256) void gemm2_kernel(
    const unsigned short* __restrict__ hbuf, const unsigned short* __restrict__ w2b,
    const int* __restrict__ cnt, const int* __restrict__ off,
    const int* __restrict__ tok_of, float* __restrict__ out) {
    const int MT = S_TOK / 128;  // 64
    const int NT = H_DIM / 128;  // 16
    int bx = xcd_swizzle(blockIdx.x, E_NUM * MT * NT);
    int e = bx / (MT * NT);
    int r = bx % (MT * NT);
    int mt = r % MT;
    int nt = r / MT;
    int C = cnt[e];
    if (mt * 128 >= C) return;
    int O = off[e];

    __shared__ __align__(16) char lds[2][32768];

    int tid = threadIdx.x;
    int wave = tid >> 6, lane = tid & 63;
    int wr = wave >> 1, wc = wave & 1;

    const char* aptr[4];
    const char* bptr[4];
#pragma unroll
    for (int i = 0; i < 4; ++i) {
        int u = (wave * 4 + i) * 64 + lane;
        int row = u >> 3;
        int cu = (u & 7) ^ (row & 7);
        int grow = mt * 128 + row; if (grow > C - 1) grow = C - 1;
        aptr[i] = (const char*)(hbuf + (size_t)(O + grow) * I_DIM + cu * 8);
        int brow = nt * 128 + row;
        bptr[i] = (const char*)(w2b + (size_t)e * H_DIM * I_DIM + (size_t)brow * I_DIM + cu * 8);
    }

    int aoff[4][2], boff[4][2];
#pragma unroll
    for (int m = 0; m < 4; ++m)
#pragma unroll
        for (int ks = 0; ks < 2; ++ks) {
            int row = wr * 64 + m * 16 + (lane & 15);
            int cu = ks * 4 + (lane >> 4);
            aoff[m][ks] = row * 128 + ((cu ^ (row & 7)) * 16);
            int brw = wc * 64 + m * 16 + (lane & 15);
            boff[m][ks] = 16384 + brw * 128 + ((cu ^ (brw & 7)) * 16);
        }

    f32x4 acc[4][4];
#pragma unroll
    for (int m = 0; m < 4; ++m)
#pragma unroll
        for (int n = 0; n < 4; ++n)
#pragma unroll
            for (int q = 0; q < 4; ++q) acc[m][n][q] = 0.0f;

    auto stage = [&](int buf, int kt) {
#pragma unroll
        for (int i = 0; i < 4; ++i)
            async_copy16(lds[buf] + (wave * 4 + i) * 1024, aptr[i] + kt * 128);
#pragma unroll
        for (int i = 0; i < 4; ++i)
            async_copy16(lds[buf] + 16384 + (wave * 4 + i) * 1024, bptr[i] + kt * 128);
    };
    auto compute = [&](int buf) {
#pragma unroll
        for (int ks = 0; ks < 2; ++ks) {
            bf16x8 a[4], b[4];
#pragma unroll
            for (int m = 0; m < 4; ++m) a[m] = *(const bf16x8*)(lds[buf] + aoff[m][ks]);
#pragma unroll
            for (int n = 0; n < 4; ++n) b[n] = *(const bf16x8*)(lds[buf] + boff[n][ks]);
#pragma unroll
            for (int m = 0; m < 4; ++m)
#pragma unroll
                for (int n = 0; n < 4; ++n)
                    acc[m][n] = __builtin_amdgcn_mfma_f32_16x16x32_bf16(a[m], b[n], acc[m][n], 0, 0, 0);
        }
    };

    stage(0, 0);
    __syncthreads();
    int cur = 0;
    for (int kt = 0; kt < I_DIM / 64 - 1; ++kt) {
        stage(cur ^ 1, kt + 1);
        asm volatile("" ::: "memory");
        compute(cur);
        __syncthreads();
        cur ^= 1;
    }
    compute(cur);

#pragma unroll
    for (int m = 0; m < 4; ++m)
#pragma unroll
        for (int q = 0; q < 4; ++q) {
            int row = mt * 128 + wr * 64 + m * 16 + (lane >> 4) * 4 + q;
            if (row < C) {
                int token = tok_of[e * S_TOK + row];
                float* op = out + (size_t)token * H_DIM + nt * 128 + wc * 64 + (lane & 15);
#pragma unroll
                for (int n = 0; n < 4; ++n)
                    unsafeAtomicAdd(op + n * 16, acc[m][n][q]);
            }
        }
}

extern "C" void kernel_launch(void* const* d_in, const int* in_sizes, int n_in,
                              void* d_out, int out_size, void* d_ws, size_t ws_size,
                              hipStream_t stream) {
    const float* hs = (const float*)d_in[0];
    const float* wg = (const float*)d_in[1];
    const float* w1 = (const float*)d_in[2];
    const float* w2 = (const float*)d_in[3];

    float* out = (float*)d_out;
    float* logits = out + (size_t)S_TOK * H_DIM;

    char* ws = (char*)d_ws;
    int* cnt = (int*)ws;
    int* off = (int*)(ws + 256);
    int* tok_of = (int*)(ws + 512);
    float* wgt_of = (float*)(ws + 512 + (size_t)E_NUM * S_TOK * 4);
    size_t o = 512 + (size_t)E_NUM * S_TOK * 8;
    o = (o + 4095) & ~(size_t)4095;
    unsigned short* hsb = (unsigned short*)(ws + o);  o += (size_t)S_TOK * H_DIM * 2;
    unsigned short* wxb = (unsigned short*)(ws + o);  o += (size_t)E_NUM * 2 * I_DIM * H_DIM * 2;
    unsigned short* hbuf = (unsigned short*)(ws + o); o += (size_t)S_TOK * 2 * I_DIM * 2;

    hipMemsetAsync(out, 0, (size_t)S_TOK * H_DIM * sizeof(float), stream);
    hipMemsetAsync(cnt, 0, 64, stream);

    cvt_kernel<<<4096, 256, 0, stream>>>(hs, hsb, (long)S_TOK * H_DIM);
    cvt_kernel<<<4096, 256, 0, stream>>>(w1, wxb, (long)E_NUM * 2 * I_DIM * H_DIM);
    router_kernel<<<S_TOK, 256, 0, stream>>>(hs, wg, logits, cnt, tok_of, wgt_of);
    offsets_kernel<<<1, 64, 0, stream>>>(cnt, off);
    gemm1_kernel<<<E_NUM * 64 * 32, 256, 0, stream>>>(hsb, wxb, cnt, off, tok_of, wgt_of, hbuf);
    cvt_kernel<<<4096, 256, 0, stream>>>(w2, wxb, (long)E_NUM * H_DIM * I_DIM);
    gemm2_kernel<<<E_NUM * 64 * 16, 256, 0, stream>>>(hbuf, wxb, cnt, off, tok_of, out);
}

// Round 3
// 831.308 us; speedup vs baseline: 1.7014x; 1.1308x over previous
//
#include <hip/hip_runtime.h>
#include <hip/hip_bf16.h>
#include <stdint.h>

#define S_TOK 8192
#define H_DIM 2048
#define I_DIM 2048
#define E_NUM 8

typedef __attribute__((ext_vector_type(4))) float f32x4;
typedef __attribute__((ext_vector_type(8))) short bf16x8;

#define MFMA16(a, b, c) __builtin_amdgcn_mfma_f32_16x16x32_bf16((a), (b), (c), 0, 0, 0)

// f32 -> bf16 RNE
__device__ __forceinline__ unsigned short f2bf(float f) {
    unsigned int u = __float_as_uint(f);
    unsigned int r = (u + 0x7FFFu + ((u >> 16) & 1u)) >> 16;
    return (unsigned short)r;
}

// async global->LDS, 16B per lane. LDS dest is wave-uniform base + lane*16.
__device__ __forceinline__ void async_copy16(void* lds, const void* g) {
    __builtin_amdgcn_global_load_lds(
        (const __attribute__((address_space(1))) void*)(uintptr_t)g,
        (__attribute__((address_space(3))) void*)(uintptr_t)lds,
        16, 0, 0);
}

// XCD-aware block swizzle (grid % 8 == 0 for all our grids)
__device__ __forceinline__ int xcd_swizzle(int bid, int nwg) {
    int cpx = nwg >> 3;
    return (bid & 7) * cpx + (bid >> 3);
}

// ---------------- f32 -> bf16 conversion ----------------
__global__ void cvt_kernel(const float* __restrict__ src, unsigned short* __restrict__ dst, long n) {
    long i0 = ((long)blockIdx.x * blockDim.x + threadIdx.x) * 4;
    long stride = (long)gridDim.x * blockDim.x * 4;
    for (long i = i0; i < n; i += stride) {
        float4 v = *(const float4*)(src + i);
        ushort4 o;
        o.x = f2bf(v.x); o.y = f2bf(v.y); o.z = f2bf(v.z); o.w = f2bf(v.w);
        *(ushort4*)(dst + i) = o;
    }
}

// ---------------- router: logits (f32 exact), top-2, expert lists ----------------
__global__ void router_kernel(const float* __restrict__ hs, const float* __restrict__ wg,
                              float* __restrict__ logits, int* __restrict__ cnt,
                              int* __restrict__ tok_of, float* __restrict__ wgt_of) {
    int t = blockIdx.x;
    int tid = threadIdx.x;
    const float* hrow = hs + (size_t)t * H_DIM;
    float4 h0 = *(const float4*)(hrow + tid * 8);
    float4 h1 = *(const float4*)(hrow + tid * 8 + 4);
    float p[E_NUM];
#pragma unroll
    for (int e = 0; e < E_NUM; ++e) {
        const float* w = wg + (size_t)e * H_DIM + tid * 8;
        float4 w0 = *(const float4*)(w);
        float4 w1v = *(const float4*)(w + 4);
        p[e] = h0.x * w0.x + h0.y * w0.y + h0.z * w0.z + h0.w * w0.w +
               h1.x * w1v.x + h1.y * w1v.y + h1.z * w1v.z + h1.w * w1v.w;
    }
#pragma unroll
    for (int e = 0; e < E_NUM; ++e)
#pragma unroll
        for (int d = 32; d > 0; d >>= 1) p[e] += __shfl_xor(p[e], d, 64);

    __shared__ float red[4][E_NUM];
    int wave = tid >> 6, lane = tid & 63;
    if (lane == 0) {
#pragma unroll
        for (int e = 0; e < E_NUM; ++e) red[wave][e] = p[e];
    }
    __syncthreads();
    if (tid == 0) {
        float l[E_NUM];
#pragma unroll
        for (int e = 0; e < E_NUM; ++e) l[e] = red[0][e] + red[1][e] + red[2][e] + red[3][e];
#pragma unroll
        for (int e = 0; e < E_NUM; ++e) logits[(size_t)t * E_NUM + e] = l[e];
        int i1 = 0;
#pragma unroll
        for (int e = 1; e < E_NUM; ++e) if (l[e] > l[i1]) i1 = e;
        int i2 = (i1 == 0) ? 1 : 0;
#pragma unroll
        for (int e = 0; e < E_NUM; ++e) if (e != i1 && l[e] > l[i2]) i2 = e;
        float b = __expf(l[i2] - l[i1]);
        float wA = 1.0f / (1.0f + b);
        float wB = 1.0f - wA;
        int s1 = atomicAdd(&cnt[i1], 1);
        tok_of[i1 * S_TOK + s1] = t; wgt_of[i1 * S_TOK + s1] = wA;
        int s2 = atomicAdd(&cnt[i2], 1);
        tok_of[i2 * S_TOK + s2] = t; wgt_of[i2 * S_TOK + s2] = wB;
    }
}

__global__ void offsets_kernel(const int* __restrict__ cnt, int* __restrict__ off) {
    if (threadIdx.x == 0) {
        int s = 0;
        for (int e = 0; e < E_NUM; ++e) { off[e] = s; s += cnt[e]; }
    }
}

// ---------------- 8-phase 256x256 grouped GEMM (T2+T3+T4+T5) ----------------
// BM=256, BN=256 (G1: 128 gate + 128 up interleaved), BK=64, KT=32.
// 8 waves 2Mx4N, per-wave output 128x64, acc[8][4].
// LDS: A 2x32KB + B 2x32KB = 128KB. B LDS rows permuted so np-group g
// occupies half g (gives np0 data 3 phases of landing slack).
// Pipeline per tile T (cur=T&1):
//  P1: rd B.np0+A.m0-3 | pre B(T+1)h0->B[cur^1] | mfma m0-3 x n0-1 | bar
//  P2: rd A.m4-7       | pre A(T+2)q0,q2->A[cur]| mfma m4-7 x n0-1 | vmcnt(4) bar
//  P3: rd B.np1        | pre A(T+2)q1,q3->A[cur]| mfma m0-3 x n2-3 | bar
//  P4:                 | pre B(T+1)h1->B[cur^1] | mfma m4-7 x n2-3 | vmcnt(6) bar
// Region frees: A q0,q2 end-P1; q1,q3 end-P2; B np0 end-P2(regs after P1); np1 end-P4.
template<int IS_G1>
__global__ __launch_bounds__(512, 2) void moe_gemm_kernel(
    const unsigned short* __restrict__ A_src, const unsigned short* __restrict__ W,
    const int* __restrict__ cnt, const int* __restrict__ off,
    const int* __restrict__ tok_of, const float* __restrict__ wgt_of,
    unsigned short* __restrict__ hbuf, float* __restrict__ out) {
    const int NT = IS_G1 ? 16 : 8;          // G1: 2048/128 h-cols; G2: 2048/256 cols
    const int GRID = E_NUM * 32 * NT;
    int bx = xcd_swizzle(blockIdx.x, GRID);
    int nt = bx / (E_NUM * 32);
    int rr = bx % (E_NUM * 32);
    int e = rr / 32;
    int mt = rr % 32;
    int C = cnt[e];
    if (mt * 256 >= C) return;
    int O = off[e];

    __shared__ __align__(16) char ldsA[2][32768];
    __shared__ __align__(16) char ldsB[2][32768];

    int tid = threadIdx.x;
    int wave = tid >> 6, lane = tid & 63;
    int wr = wave >> 2, wc = wave & 3;

    // ---- staging source pointers (pre-swizzled per involution rule) ----
    // A quarter q: rows [q*64, q*64+64); this wave covers 8 rows.
    const char* aptr[4];
#pragma unroll
    for (int q = 0; q < 4; ++q) {
        int row = q * 64 + wave * 8 + (lane >> 3);
        int cu = (lane & 7) ^ (row & 7);
        int grow = mt * 256 + row; if (grow > C - 1) grow = C - 1;
        size_t arow = IS_G1 ? (size_t)tok_of[e * S_TOK + grow] : (size_t)(O + grow);
        aptr[q] = (const char*)(A_src + arow * 2048 + cu * 8);
    }
    // B issue j: LDS rows [j*64, j*64+64). lrow -> tile-B-row mapping packs
    // np-group into half (lrow = np*128 + wc*32 + nb*16 + r16).
    const char* bptr[4];
#pragma unroll
    for (int j = 0; j < 4; ++j) {
        int lrow = j * 64 + wave * 8 + (lane >> 3);
        int cu = (lane & 7) ^ (lrow & 7);
        int np = lrow >> 7, wcg = (lrow >> 5) & 3, rem = lrow & 31;
        int tbrow = wcg * 64 + np * 32 + rem;
        size_t brow;
        if (IS_G1) {
            int jj = tbrow & 63, wq = tbrow >> 6;
            if (jj < 32) brow = (size_t)(nt * 128 + wq * 32 + jj);
            else         brow = (size_t)I_DIM + nt * 128 + wq * 32 + (jj - 32);
            brow += (size_t)e * (2 * I_DIM);
        } else {
            brow = (size_t)e * H_DIM + nt * 256 + tbrow;
        }
        bptr[j] = (const char*)(W + brow * 2048 + cu * 8);
    }

    // ---- swizzled ds_read byte offsets ----
    int aoff[8][2], boff[4][2];
#pragma unroll
    for (int m = 0; m < 8; ++m)
#pragma unroll
        for (int ks = 0; ks < 2; ++ks) {
            int row = wr * 128 + m * 16 + (lane & 15);
            int cu = ks * 4 + (lane >> 4);
            aoff[m][ks] = row * 128 + ((cu ^ (row & 7)) * 16);
        }
#pragma unroll
    for (int n = 0; n < 4; ++n)
#pragma unroll
        for (int ks = 0; ks < 2; ++ks) {
            int lrow = (n >> 1) * 128 + wc * 32 + (n & 1) * 16 + (lane & 15);
            int cu = ks * 4 + (lane >> 4);
            boff[n][ks] = lrow * 128 + ((cu ^ (lrow & 7)) * 16);
        }

    f32x4 acc[8][4];
#pragma unroll
    for (int m = 0; m < 8; ++m)
#pragma unroll
        for (int n = 0; n < 4; ++n)
#pragma unroll
            for (int q = 0; q < 4; ++q) acc[m][n][q] = 0.0f;

    auto gA = [&](int q, int T, int buf) {
        async_copy16(ldsA[buf] + q * 8192 + wave * 1024, aptr[q] + T * 128);
    };
    auto gB = [&](int j, int T, int buf) {
        async_copy16(ldsB[buf] + j * 8192 + wave * 1024, bptr[j] + T * 128);
    };

    // ---- prologue: establish steady-state queue ----
    // order: A0(q0,q2,q1,q3) B0h0(j0,j1) A1(q0,q2,q1,q3) B0h1(j2,j3)
    gA(0, 0, 0); gA(2, 0, 0); gA(1, 0, 0); gA(3, 0, 0);
    gB(0, 0, 0); gB(1, 0, 0);
    gA(0, 1, 1); gA(2, 1, 1); gA(1, 1, 1); gA(3, 1, 1);
    gB(2, 0, 0); gB(3, 0, 0);
    asm volatile("s_waitcnt vmcnt(6)" ::: "memory");
    __builtin_amdgcn_s_barrier();

    bf16x8 ar[8][2], br[2][2];
    int cur = 0;
#pragma unroll 2
    for (int T = 0; T < 32; ++T) {
        int nxt = cur ^ 1;
        int TA = (T + 2 < 32) ? T + 2 : 31;
        int TB = (T + 1 < 32) ? T + 1 : 31;
        // ---- P1 ----
#pragma unroll
        for (int n = 0; n < 2; ++n)
#pragma unroll
            for (int ks = 0; ks < 2; ++ks)
                br[n][ks] = *(const bf16x8*)(ldsB[cur] + boff[n][ks]);
#pragma unroll
        for (int m = 0; m < 4; ++m)
#pragma unroll
            for (int ks = 0; ks < 2; ++ks)
                ar[m][ks] = *(const bf16x8*)(ldsA[cur] + aoff[m][ks]);
        gB(0, TB, nxt); gB(1, TB, nxt);
        __builtin_amdgcn_s_setprio(1);
#pragma unroll
        for (int m = 0; m < 4; ++m)
#pragma unroll
            for (int n = 0; n < 2; ++n) {
                acc[m][n] = MFMA16(ar[m][0], br[n][0], acc[m][n]);
                acc[m][n] = MFMA16(ar[m][1], br[n][1], acc[m][n]);
            }
        __builtin_amdgcn_s_setprio(0);
        __builtin_amdgcn_s_barrier();
        // ---- P2 ----
#pragma unroll
        for (int m = 4; m < 8; ++m)
#pragma unroll
            for (int ks = 0; ks < 2; ++ks)
                ar[m][ks] = *(const bf16x8*)(ldsA[cur] + aoff[m][ks]);
        gA(0, TA, cur); gA(2, TA, cur);
        __builtin_amdgcn_s_setprio(1);
#pragma unroll
        for (int m = 4; m < 8; ++m)
#pragma unroll
            for (int n = 0; n < 2; ++n) {
                acc[m][n] = MFMA16(ar[m][0], br[n][0], acc[m][n]);
                acc[m][n] = MFMA16(ar[m][1], br[n][1], acc[m][n]);
            }
        __builtin_amdgcn_s_setprio(0);
        asm volatile("s_waitcnt vmcnt(4)" ::: "memory");
        __builtin_amdgcn_s_barrier();
        // ---- P3 ----
#pragma unroll
        for (int n = 0; n < 2; ++n)
#pragma unroll
            for (int ks = 0; ks < 2; ++ks)
                br[n][ks] = *(const bf16x8*)(ldsB[cur] + boff[n + 2][ks]);
        gA(1, TA, cur); gA(3, TA, cur);
        __builtin_amdgcn_s_setprio(1);
#pragma unroll
        for (int m = 0; m < 4; ++m)
#pragma unroll
            for (int n = 0; n < 2; ++n) {
                acc[m][n + 2] = MFMA16(ar[m][0], br[n][0], acc[m][n + 2]);
                acc[m][n + 2] = MFMA16(ar[m][1], br[n][1], acc[m][n + 2]);
            }
        __builtin_amdgcn_s_setprio(0);
        __builtin_amdgcn_s_barrier();
        // ---- P4 ----
        gB(2, TB, nxt); gB(3, TB, nxt);
        __builtin_amdgcn_s_setprio(1);
#pragma unroll
        for (int m = 4; m < 8; ++m)
#pragma unroll
            for (int n = 0; n < 2; ++n) {
                acc[m][n + 2] = MFMA16(ar[m][0], br[n][0], acc[m][n + 2]);
                acc[m][n + 2] = MFMA16(ar[m][1], br[n][1], acc[m][n + 2]);
            }
        __builtin_amdgcn_s_setprio(0);
        asm volatile("s_waitcnt vmcnt(6)" ::: "memory");
        __builtin_amdgcn_s_barrier();
        cur = nxt;
    }

    // ---- epilogue ----
    if (IS_G1) {
#pragma unroll
        for (int m = 0; m < 8; ++m)
#pragma unroll
            for (int q = 0; q < 4; ++q) {
                int row = mt * 256 + wr * 128 + m * 16 + (lane >> 4) * 4 + q;
                if (row < C) {
                    float wgt = wgt_of[e * S_TOK + row];
                    unsigned short* hp = hbuf + (size_t)(O + row) * I_DIM +
                                         nt * 128 + wc * 32 + (lane & 15);
#pragma unroll
                    for (int n = 0; n < 2; ++n) {
                        float g = acc[m][n][q];
                        float u = acc[m][n + 2][q];
                        float hv = (g / (1.0f + __expf(-g))) * u * wgt;
                        hp[n * 16] = f2bf(hv);
                    }
                }
            }
    } else {
#pragma unroll
        for (int m = 0; m < 8; ++m)
#pragma unroll
            for (int q = 0; q < 4; ++q) {
                int row = mt * 256 + wr * 128 + m * 16 + (lane >> 4) * 4 + q;
                if (row < C) {
                    int token = tok_of[e * S_TOK + row];
                    float* op = out + (size_t)token * H_DIM + nt * 256 + wc * 64 + (lane & 15);
#pragma unroll
                    for (int n = 0; n < 4; ++n)
                        unsafeAtomicAdd(op + n * 16, acc[m][n][q]);
                }
            }
    }
}

extern "C" void kernel_launch(void* const* d_in, const int* in_sizes, int n_in,
                              void* d_out, int out_size, void* d_ws, size_t ws_size,
                              hipStream_t stream) {
    const float* hs = (const float*)d_in[0];
    const float* wg = (const float*)d_in[1];
    const float* w1 = (const float*)d_in[2];
    const float* w2 = (const float*)d_in[3];

    float* out = (float*)d_out;
    float* logits = out + (size_t)S_TOK * H_DIM;

    char* ws = (char*)d_ws;
    int* cnt = (int*)ws;
    int* off = (int*)(ws + 256);
    int* tok_of = (int*)(ws + 512);
    float* wgt_of = (float*)(ws + 512 + (size_t)E_NUM * S_TOK * 4);
    size_t o = 512 + (size_t)E_NUM * S_TOK * 8;
    o = (o + 4095) & ~(size_t)4095;
    unsigned short* hsb = (unsigned short*)(ws + o);  o += (size_t)S_TOK * H_DIM * 2;
    unsigned short* wxb = (unsigned short*)(ws + o);  o += (size_t)E_NUM * 2 * I_DIM * H_DIM * 2;
    unsigned short* hbuf = (unsigned short*)(ws + o); o += (size_t)S_TOK * 2 * I_DIM * 2;

    hipMemsetAsync(out, 0, (size_t)S_TOK * H_DIM * sizeof(float), stream);
    hipMemsetAsync(cnt, 0, 64, stream);

    cvt_kernel<<<4096, 256, 0, stream>>>(hs, hsb, (long)S_TOK * H_DIM);
    cvt_kernel<<<4096, 256, 0, stream>>>(w1, wxb, (long)E_NUM * 2 * I_DIM * H_DIM);
    router_kernel<<<S_TOK, 256, 0, stream>>>(hs, wg, logits, cnt, tok_of, wgt_of);
    offsets_kernel<<<1, 64, 0, stream>>>(cnt, off);
    moe_gemm_kernel<1><<<E_NUM * 32 * 16, 512, 0, stream>>>(hsb, wxb, cnt, off, tok_of, wgt_of, hbuf, out);
    cvt_kernel<<<4096, 256, 0, stream>>>(w2, wxb, (long)E_NUM * H_DIM * I_DIM);
    moe_gemm_kernel<0><<<E_NUM * 32 * 8, 512, 0, stream>>>(hbuf, wxb, cnt, off, tok_of, wgt_of, hbuf, out);
}

// Round 4
// 768.212 us; speedup vs baseline: 1.8411x; 1.0821x over previous
//
#include <hip/hip_runtime.h>
#include <hip/hip_bf16.h>
#include <stdint.h>

#define S_TOK 8192
#define H_DIM 2048
#define I_DIM 2048
#define E_NUM 8

typedef __attribute__((ext_vector_type(4))) float f32x4;
typedef __attribute__((ext_vector_type(8))) short bf16x8;

#define MFMA16(a, b, c) __builtin_amdgcn_mfma_f32_16x16x32_bf16((a), (b), (c), 0, 0, 0)

// f32 -> bf16 RNE
__device__ __forceinline__ unsigned short f2bf(float f) {
    unsigned int u = __float_as_uint(f);
    unsigned int r = (u + 0x7FFFu + ((u >> 16) & 1u)) >> 16;
    return (unsigned short)r;
}
__device__ __forceinline__ float bf2f(unsigned short u) {
    return __uint_as_float((unsigned int)u << 16);
}

// async global->LDS, 16B per lane. LDS dest is wave-uniform base + lane*16.
__device__ __forceinline__ void async_copy16(void* lds, const void* g) {
    __builtin_amdgcn_global_load_lds(
        (const __attribute__((address_space(1))) void*)(uintptr_t)g,
        (__attribute__((address_space(3))) void*)(uintptr_t)lds,
        16, 0, 0);
}

// XCD-aware block swizzle (grid % 8 == 0 for all our grids)
__device__ __forceinline__ int xcd_swizzle(int bid, int nwg) {
    int cpx = nwg >> 3;
    return (bid & 7) * cpx + (bid >> 3);
}

// ---------------- f32 -> bf16 conversion (weights) ----------------
__global__ void cvt_kernel(const float* __restrict__ src, unsigned short* __restrict__ dst, long n) {
    long i0 = ((long)blockIdx.x * blockDim.x + threadIdx.x) * 4;
    long stride = (long)gridDim.x * blockDim.x * 4;
    for (long i = i0; i < n; i += stride) {
        float4 v = *(const float4*)(src + i);
        ushort4 o;
        o.x = f2bf(v.x); o.y = f2bf(v.y); o.z = f2bf(v.z); o.w = f2bf(v.w);
        *(ushort4*)(dst + i) = o;
    }
}

// ---------------- router: logits (f32 exact), top-2, lists, hs->bf16 ----------------
__global__ void router_kernel(const float* __restrict__ hs, const float* __restrict__ wg,
                              float* __restrict__ logits, int* __restrict__ cnt,
                              int* __restrict__ tok_of, float* __restrict__ wgt_of,
                              unsigned int* __restrict__ slot_of,
                              unsigned short* __restrict__ hsb) {
    int t = blockIdx.x;
    int tid = threadIdx.x;
    const float* hrow = hs + (size_t)t * H_DIM;
    float4 h0 = *(const float4*)(hrow + tid * 8);
    float4 h1 = *(const float4*)(hrow + tid * 8 + 4);
    // fused hs -> bf16
    ushort4 oA, oB;
    oA.x = f2bf(h0.x); oA.y = f2bf(h0.y); oA.z = f2bf(h0.z); oA.w = f2bf(h0.w);
    oB.x = f2bf(h1.x); oB.y = f2bf(h1.y); oB.z = f2bf(h1.z); oB.w = f2bf(h1.w);
    *(ushort4*)(hsb + (size_t)t * H_DIM + tid * 8) = oA;
    *(ushort4*)(hsb + (size_t)t * H_DIM + tid * 8 + 4) = oB;

    float p[E_NUM];
#pragma unroll
    for (int e = 0; e < E_NUM; ++e) {
        const float* w = wg + (size_t)e * H_DIM + tid * 8;
        float4 w0 = *(const float4*)(w);
        float4 w1v = *(const float4*)(w + 4);
        p[e] = h0.x * w0.x + h0.y * w0.y + h0.z * w0.z + h0.w * w0.w +
               h1.x * w1v.x + h1.y * w1v.y + h1.z * w1v.z + h1.w * w1v.w;
    }
#pragma unroll
    for (int e = 0; e < E_NUM; ++e)
#pragma unroll
        for (int d = 32; d > 0; d >>= 1) p[e] += __shfl_xor(p[e], d, 64);

    __shared__ float red[4][E_NUM];
    int wave = tid >> 6, lane = tid & 63;
    if (lane == 0) {
#pragma unroll
        for (int e = 0; e < E_NUM; ++e) red[wave][e] = p[e];
    }
    __syncthreads();
    if (tid == 0) {
        float l[E_NUM];
#pragma unroll
        for (int e = 0; e < E_NUM; ++e) l[e] = red[0][e] + red[1][e] + red[2][e] + red[3][e];
#pragma unroll
        for (int e = 0; e < E_NUM; ++e) logits[(size_t)t * E_NUM + e] = l[e];
        int i1 = 0;
#pragma unroll
        for (int e = 1; e < E_NUM; ++e) if (l[e] > l[i1]) i1 = e;
        int i2 = (i1 == 0) ? 1 : 0;
#pragma unroll
        for (int e = 0; e < E_NUM; ++e) if (e != i1 && l[e] > l[i2]) i2 = e;
        float b = __expf(l[i2] - l[i1]);
        float wA = 1.0f / (1.0f + b);
        float wB = 1.0f - wA;
        int s1 = atomicAdd(&cnt[i1], 1);
        tok_of[i1 * S_TOK + s1] = t; wgt_of[i1 * S_TOK + s1] = wA;
        int s2 = atomicAdd(&cnt[i2], 1);
        tok_of[i2 * S_TOK + s2] = t; wgt_of[i2 * S_TOK + s2] = wB;
        slot_of[2 * t]     = ((unsigned)i1 << 20) | (unsigned)s1;
        slot_of[2 * t + 1] = ((unsigned)i2 << 20) | (unsigned)s2;
    }
}

__global__ void offsets_kernel(const int* __restrict__ cnt, int* __restrict__ off) {
    if (threadIdx.x == 0) {
        int s = 0;
        for (int e = 0; e < E_NUM; ++e) { off[e] = s; s += cnt[e]; }
    }
}

// ---------------- combine: out[t] = pbuf[slotA] + pbuf[slotB] ----------------
__global__ void combine_kernel(const unsigned short* __restrict__ pbuf,
                               const unsigned int* __restrict__ slot_of,
                               const int* __restrict__ off, float* __restrict__ out) {
    int t = blockIdx.x, tid = threadIdx.x;
    unsigned int a = slot_of[2 * t], b = slot_of[2 * t + 1];
    size_t ra = (size_t)(off[a >> 20] + (int)(a & 0xFFFFFu));
    size_t rb = (size_t)(off[b >> 20] + (int)(b & 0xFFFFFu));
    const unsigned short* pa = pbuf + ra * H_DIM + tid * 8;
    const unsigned short* pb = pbuf + rb * H_DIM + tid * 8;
    ushort4 a0 = *(const ushort4*)pa,        a1 = *(const ushort4*)(pa + 4);
    ushort4 b0 = *(const ushort4*)pb,        b1 = *(const ushort4*)(pb + 4);
    float4 r0, r1;
    r0.x = bf2f(a0.x) + bf2f(b0.x); r0.y = bf2f(a0.y) + bf2f(b0.y);
    r0.z = bf2f(a0.z) + bf2f(b0.z); r0.w = bf2f(a0.w) + bf2f(b0.w);
    r1.x = bf2f(a1.x) + bf2f(b1.x); r1.y = bf2f(a1.y) + bf2f(b1.y);
    r1.z = bf2f(a1.z) + bf2f(b1.z); r1.w = bf2f(a1.w) + bf2f(b1.w);
    float* op = out + (size_t)t * H_DIM + tid * 8;
    *(float4*)op = r0;
    *(float4*)(op + 4) = r1;
}

// ---------------- 8-phase 256x256 grouped GEMM (T2+T3+T4+T5) ----------------
// Same tiling/queue math as round 3; phase rhythm now matches m201:
//   {ds_read | stage | BAR | MFMA(prio1) | [vmcnt] | BAR}
// so ds_read latency lands under the mid-phase barrier instead of in front
// of the MFMA cluster.
// G1 epilogue: silu(gate)*up*wgt -> bf16 hbuf. G2 epilogue: bf16 partial rows.
template<int IS_G1>
__global__ __launch_bounds__(512, 2) void moe_gemm_kernel(
    const unsigned short* __restrict__ A_src, const unsigned short* __restrict__ W,
    const int* __restrict__ cnt, const int* __restrict__ off,
    const int* __restrict__ tok_of, const float* __restrict__ wgt_of,
    unsigned short* __restrict__ dst) {
    const int NT = IS_G1 ? 16 : 8;
    const int GRID = E_NUM * 32 * NT;
    int bx = xcd_swizzle(blockIdx.x, GRID);
    int nt = bx / (E_NUM * 32);
    int rr = bx % (E_NUM * 32);
    int e = rr / 32;
    int mt = rr % 32;
    int C = cnt[e];
    if (mt * 256 >= C) return;
    int O = off[e];

    __shared__ __align__(16) char ldsA[2][32768];
    __shared__ __align__(16) char ldsB[2][32768];

    int tid = threadIdx.x;
    int wave = tid >> 6, lane = tid & 63;
    int wr = wave >> 2, wc = wave & 3;

    // ---- staging source pointers (pre-swizzled involution) ----
    const char* aptr[4];
#pragma unroll
    for (int q = 0; q < 4; ++q) {
        int row = q * 64 + wave * 8 + (lane >> 3);
        int cu = (lane & 7) ^ (row & 7);
        int grow = mt * 256 + row; if (grow > C - 1) grow = C - 1;
        size_t arow = IS_G1 ? (size_t)tok_of[e * S_TOK + grow] : (size_t)(O + grow);
        aptr[q] = (const char*)(A_src + arow * 2048 + cu * 8);
    }
    const char* bptr[4];
#pragma unroll
    for (int j = 0; j < 4; ++j) {
        int lrow = j * 64 + wave * 8 + (lane >> 3);
        int cu = (lane & 7) ^ (lrow & 7);
        int np = lrow >> 7, wcg = (lrow >> 5) & 3, rem = lrow & 31;
        int tbrow = wcg * 64 + np * 32 + rem;
        size_t brow;
        if (IS_G1) {
            int jj = tbrow & 63, wq = tbrow >> 6;
            if (jj < 32) brow = (size_t)(nt * 128 + wq * 32 + jj);
            else         brow = (size_t)I_DIM + nt * 128 + wq * 32 + (jj - 32);
            brow += (size_t)e * (2 * I_DIM);
        } else {
            brow = (size_t)e * H_DIM + nt * 256 + tbrow;
        }
        bptr[j] = (const char*)(W + brow * 2048 + cu * 8);
    }

    // ---- swizzled ds_read byte offsets ----
    int aoff[8][2], boff[4][2];
#pragma unroll
    for (int m = 0; m < 8; ++m)
#pragma unroll
        for (int ks = 0; ks < 2; ++ks) {
            int row = wr * 128 + m * 16 + (lane & 15);
            int cu = ks * 4 + (lane >> 4);
            aoff[m][ks] = row * 128 + ((cu ^ (row & 7)) * 16);
        }
#pragma unroll
    for (int n = 0; n < 4; ++n)
#pragma unroll
        for (int ks = 0; ks < 2; ++ks) {
            int lrow = (n >> 1) * 128 + wc * 32 + (n & 1) * 16 + (lane & 15);
            int cu = ks * 4 + (lane >> 4);
            boff[n][ks] = lrow * 128 + ((cu ^ (lrow & 7)) * 16);
        }

    f32x4 acc[8][4];
#pragma unroll
    for (int m = 0; m < 8; ++m)
#pragma unroll
        for (int n = 0; n < 4; ++n)
#pragma unroll
            for (int q = 0; q < 4; ++q) acc[m][n][q] = 0.0f;

    auto gA = [&](int q, int T, int buf) {
        async_copy16(ldsA[buf] + q * 8192 + wave * 1024, aptr[q] + T * 128);
    };
    auto gB = [&](int j, int T, int buf) {
        async_copy16(ldsB[buf] + j * 8192 + wave * 1024, bptr[j] + T * 128);
    };

    // ---- prologue: A0(q0,q2,q1,q3) B0h0 A1(all) B0h1 ----
    gA(0, 0, 0); gA(2, 0, 0); gA(1, 0, 0); gA(3, 0, 0);
    gB(0, 0, 0); gB(1, 0, 0);
    gA(0, 1, 1); gA(2, 1, 1); gA(1, 1, 1); gA(3, 1, 1);
    gB(2, 0, 0); gB(3, 0, 0);
    asm volatile("s_waitcnt vmcnt(6)" ::: "memory");
    __builtin_amdgcn_s_barrier();

    bf16x8 ar[8][2], br[2][2];
    int cur = 0;
#pragma unroll 2
    for (int T = 0; T < 32; ++T) {
        int nxt = cur ^ 1;
        int TA = (T + 2 < 32) ? T + 2 : 31;
        int TB = (T + 1 < 32) ? T + 1 : 31;
        // ---- P1: rd B.np0 + A.m0-3 | gB h0(T+1) | bar | mfma | bar ----
#pragma unroll
        for (int n = 0; n < 2; ++n)
#pragma unroll
            for (int ks = 0; ks < 2; ++ks)
                br[n][ks] = *(const bf16x8*)(ldsB[cur] + boff[n][ks]);
#pragma unroll
        for (int m = 0; m < 4; ++m)
#pragma unroll
            for (int ks = 0; ks < 2; ++ks)
                ar[m][ks] = *(const bf16x8*)(ldsA[cur] + aoff[m][ks]);
        gB(0, TB, nxt); gB(1, TB, nxt);
        __builtin_amdgcn_s_barrier();
        __builtin_amdgcn_s_setprio(1);
#pragma unroll
        for (int m = 0; m < 4; ++m)
#pragma unroll
            for (int n = 0; n < 2; ++n) {
                acc[m][n] = MFMA16(ar[m][0], br[n][0], acc[m][n]);
                acc[m][n] = MFMA16(ar[m][1], br[n][1], acc[m][n]);
            }
        __builtin_amdgcn_s_setprio(0);
        __builtin_amdgcn_s_barrier();
        // ---- P2: rd A.m4-7 | gA q0,q2(T+2) | bar | mfma | vmcnt(4) bar ----
#pragma unroll
        for (int m = 4; m < 8; ++m)
#pragma unroll
            for (int ks = 0; ks < 2; ++ks)
                ar[m][ks] = *(const bf16x8*)(ldsA[cur] + aoff[m][ks]);
        gA(0, TA, cur); gA(2, TA, cur);
        __builtin_amdgcn_s_barrier();
        __builtin_amdgcn_s_setprio(1);
#pragma unroll
        for (int m = 4; m < 8; ++m)
#pragma unroll
            for (int n = 0; n < 2; ++n) {
                acc[m][n] = MFMA16(ar[m][0], br[n][0], acc[m][n]);
                acc[m][n] = MFMA16(ar[m][1], br[n][1], acc[m][n]);
            }
        __builtin_amdgcn_s_setprio(0);
        asm volatile("s_waitcnt vmcnt(4)" ::: "memory");
        __builtin_amdgcn_s_barrier();
        // ---- P3: rd B.np1 | gA q1,q3(T+2) | bar | mfma | bar ----
#pragma unroll
        for (int n = 0; n < 2; ++n)
#pragma unroll
            for (int ks = 0; ks < 2; ++ks)
                br[n][ks] = *(const bf16x8*)(ldsB[cur] + boff[n + 2][ks]);
        gA(1, TA, cur); gA(3, TA, cur);
        __builtin_amdgcn_s_barrier();
        __builtin_amdgcn_s_setprio(1);
#pragma unroll
        for (int m = 0; m < 4; ++m)
#pragma unroll
            for (int n = 0; n < 2; ++n) {
                acc[m][n + 2] = MFMA16(ar[m][0], br[n][0], acc[m][n + 2]);
                acc[m][n + 2] = MFMA16(ar[m][1], br[n][1], acc[m][n + 2]);
            }
        __builtin_amdgcn_s_setprio(0);
        __builtin_amdgcn_s_barrier();
        // ---- P4: gB h1(T+1) | bar | mfma | vmcnt(6) bar ----
        gB(2, TB, nxt); gB(3, TB, nxt);
        __builtin_amdgcn_s_barrier();
        __builtin_amdgcn_s_setprio(1);
#pragma unroll
        for (int m = 4; m < 8; ++m)
#pragma unroll
            for (int n = 0; n < 2; ++n) {
                acc[m][n + 2] = MFMA16(ar[m][0], br[n][0], acc[m][n + 2]);
                acc[m][n + 2] = MFMA16(ar[m][1], br[n][1], acc[m][n + 2]);
            }
        __builtin_amdgcn_s_setprio(0);
        asm volatile("s_waitcnt vmcnt(6)" ::: "memory");
        __builtin_amdgcn_s_barrier();
        cur = nxt;
    }

    // ---- epilogue ----
    if (IS_G1) {
#pragma unroll
        for (int m = 0; m < 8; ++m)
#pragma unroll
            for (int q = 0; q < 4; ++q) {
                int row = mt * 256 + wr * 128 + m * 16 + (lane >> 4) * 4 + q;
                if (row < C) {
                    float wgt = wgt_of[e * S_TOK + row];
                    unsigned short* hp = dst + (size_t)(O + row) * I_DIM +
                                         nt * 128 + wc * 32 + (lane & 15);
#pragma unroll
                    for (int n = 0; n < 2; ++n) {
                        float g = acc[m][n][q];
                        float u = acc[m][n + 2][q];
                        float hv = (g / (1.0f + __expf(-g))) * u * wgt;
                        hp[n * 16] = f2bf(hv);
                    }
                }
            }
    } else {
#pragma unroll
        for (int m = 0; m < 8; ++m)
#pragma unroll
            for (int q = 0; q < 4; ++q) {
                int row = mt * 256 + wr * 128 + m * 16 + (lane >> 4) * 4 + q;
                if (row < C) {
                    unsigned short* pp = dst + (size_t)(O + row) * H_DIM +
                                         nt * 256 + wc * 64 + (lane & 15);
#pragma unroll
                    for (int n = 0; n < 4; ++n)
                        pp[n * 16] = f2bf(acc[m][n][q]);
                }
            }
    }
}

extern "C" void kernel_launch(void* const* d_in, const int* in_sizes, int n_in,
                              void* d_out, int out_size, void* d_ws, size_t ws_size,
                              hipStream_t stream) {
    const float* hs = (const float*)d_in[0];
    const float* wg = (const float*)d_in[1];
    const float* w1 = (const float*)d_in[2];
    const float* w2 = (const float*)d_in[3];

    float* out = (float*)d_out;
    float* logits = out + (size_t)S_TOK * H_DIM;

    char* ws = (char*)d_ws;
    int* cnt = (int*)ws;
    int* off = (int*)(ws + 256);
    int* tok_of = (int*)(ws + 512);
    float* wgt_of = (float*)(ws + 512 + (size_t)E_NUM * S_TOK * 4);
    unsigned int* slot_of = (unsigned int*)(ws + 512 + (size_t)E_NUM * S_TOK * 8);
    size_t o = 512 + (size_t)E_NUM * S_TOK * 8 + (size_t)S_TOK * 8;
    o = (o + 4095) & ~(size_t)4095;
    unsigned short* hsb = (unsigned short*)(ws + o);  o += (size_t)S_TOK * H_DIM * 2;            // 32 MiB
    unsigned short* wxb = (unsigned short*)(ws + o);  o += (size_t)E_NUM * 2 * I_DIM * H_DIM * 2; // 128 MiB
    unsigned short* hbuf = (unsigned short*)(ws + o); o += (size_t)S_TOK * 2 * I_DIM * 2;         // 64 MiB
    // partials reuse the idle upper half of wxb (w2 occupies only the first 64 MiB)
    unsigned short* pbuf = wxb + (size_t)E_NUM * H_DIM * I_DIM;

    hipMemsetAsync(cnt, 0, 64, stream);

    router_kernel<<<S_TOK, 256, 0, stream>>>(hs, wg, logits, cnt, tok_of, wgt_of, slot_of, hsb);
    offsets_kernel<<<1, 64, 0, stream>>>(cnt, off);
    cvt_kernel<<<4096, 256, 0, stream>>>(w1, wxb, (long)E_NUM * 2 * I_DIM * H_DIM);
    moe_gemm_kernel<1><<<E_NUM * 32 * 16, 512, 0, stream>>>(hsb, wxb, cnt, off, tok_of, wgt_of, hbuf);
    cvt_kernel<<<4096, 256, 0, stream>>>(w2, wxb, (long)E_NUM * H_DIM * I_DIM);
    moe_gemm_kernel<0><<<E_NUM * 32 * 8, 512, 0, stream>>>(hbuf, wxb, cnt, off, tok_of, wgt_of, pbuf);
    combine_kernel<<<S_TOK, 256, 0, stream>>>(pbuf, slot_of, off, out);
}

// Round 5
// 753.739 us; speedup vs baseline: 1.8765x; 1.0192x over previous
//
#include <hip/hip_runtime.h>
#include <hip/hip_bf16.h>
#include <stdint.h>

#define S_TOK 8192
#define H_DIM 2048
#define I_DIM 2048
#define E_NUM 8

typedef __attribute__((ext_vector_type(4))) float f32x4;
typedef __attribute__((ext_vector_type(8))) short bf16x8;

#define MFMA16(a, b, c) __builtin_amdgcn_mfma_f32_16x16x32_bf16((a), (b), (c), 0, 0, 0)

// f32 -> bf16 RNE
__device__ __forceinline__ unsigned short f2bf(float f) {
    unsigned int u = __float_as_uint(f);
    unsigned int r = (u + 0x7FFFu + ((u >> 16) & 1u)) >> 16;
    return (unsigned short)r;
}
__device__ __forceinline__ float bf2f(unsigned short u) {
    return __uint_as_float((unsigned int)u << 16);
}

// async global->LDS, 16B per lane. LDS dest is wave-uniform base + lane*16.
__device__ __forceinline__ void async_copy16(void* lds, const void* g) {
    __builtin_amdgcn_global_load_lds(
        (const __attribute__((address_space(1))) void*)(uintptr_t)g,
        (__attribute__((address_space(3))) void*)(uintptr_t)lds,
        16, 0, 0);
}

// XCD-aware block swizzle (nwg % 8 == 0 for all our grids)
__device__ __forceinline__ int xcd_swizzle(int bid, int nwg) {
    int cpx = nwg >> 3;
    return (bid & 7) * cpx + (bid >> 3);
}

// ---------------- f32 -> bf16 conversion (weights) ----------------
__global__ void cvt_kernel(const float* __restrict__ src, unsigned short* __restrict__ dst, long n) {
    long i0 = ((long)blockIdx.x * blockDim.x + threadIdx.x) * 4;
    long stride = (long)gridDim.x * blockDim.x * 4;
    for (long i = i0; i < n; i += stride) {
        float4 v = *(const float4*)(src + i);
        ushort4 o;
        o.x = f2bf(v.x); o.y = f2bf(v.y); o.z = f2bf(v.z); o.w = f2bf(v.w);
        *(ushort4*)(dst + i) = o;
    }
}

// ---------------- router: logits (f32 exact), top-2, lists, hs->bf16 ----------------
__global__ void router_kernel(const float* __restrict__ hs, const float* __restrict__ wg,
                              float* __restrict__ logits, int* __restrict__ cnt,
                              int* __restrict__ tok_of, float* __restrict__ wgt_of,
                              unsigned int* __restrict__ slot_of,
                              unsigned short* __restrict__ hsb) {
    int t = blockIdx.x;
    int tid = threadIdx.x;
    const float* hrow = hs + (size_t)t * H_DIM;
    float4 h0 = *(const float4*)(hrow + tid * 8);
    float4 h1 = *(const float4*)(hrow + tid * 8 + 4);
    ushort4 oA, oB;
    oA.x = f2bf(h0.x); oA.y = f2bf(h0.y); oA.z = f2bf(h0.z); oA.w = f2bf(h0.w);
    oB.x = f2bf(h1.x); oB.y = f2bf(h1.y); oB.z = f2bf(h1.z); oB.w = f2bf(h1.w);
    *(ushort4*)(hsb + (size_t)t * H_DIM + tid * 8) = oA;
    *(ushort4*)(hsb + (size_t)t * H_DIM + tid * 8 + 4) = oB;

    float p[E_NUM];
#pragma unroll
    for (int e = 0; e < E_NUM; ++e) {
        const float* w = wg + (size_t)e * H_DIM + tid * 8;
        float4 w0 = *(const float4*)(w);
        float4 w1v = *(const float4*)(w + 4);
        p[e] = h0.x * w0.x + h0.y * w0.y + h0.z * w0.z + h0.w * w0.w +
               h1.x * w1v.x + h1.y * w1v.y + h1.z * w1v.z + h1.w * w1v.w;
    }
#pragma unroll
    for (int e = 0; e < E_NUM; ++e)
#pragma unroll
        for (int d = 32; d > 0; d >>= 1) p[e] += __shfl_xor(p[e], d, 64);

    __shared__ float red[4][E_NUM];
    int wave = tid >> 6, lane = tid & 63;
    if (lane == 0) {
#pragma unroll
        for (int e = 0; e < E_NUM; ++e) red[wave][e] = p[e];
    }
    __syncthreads();
    if (tid == 0) {
        float l[E_NUM];
#pragma unroll
        for (int e = 0; e < E_NUM; ++e) l[e] = red[0][e] + red[1][e] + red[2][e] + red[3][e];
#pragma unroll
        for (int e = 0; e < E_NUM; ++e) logits[(size_t)t * E_NUM + e] = l[e];
        int i1 = 0;
#pragma unroll
        for (int e = 1; e < E_NUM; ++e) if (l[e] > l[i1]) i1 = e;
        int i2 = (i1 == 0) ? 1 : 0;
#pragma unroll
        for (int e = 0; e < E_NUM; ++e) if (e != i1 && l[e] > l[i2]) i2 = e;
        float b = __expf(l[i2] - l[i1]);
        float wA = 1.0f / (1.0f + b);
        float wB = 1.0f - wA;
        int s1 = atomicAdd(&cnt[i1], 1);
        tok_of[i1 * S_TOK + s1] = t; wgt_of[i1 * S_TOK + s1] = wA;
        int s2 = atomicAdd(&cnt[i2], 1);
        tok_of[i2 * S_TOK + s2] = t; wgt_of[i2 * S_TOK + s2] = wB;
        slot_of[2 * t]     = ((unsigned)i1 << 20) | (unsigned)s1;
        slot_of[2 * t + 1] = ((unsigned)i2 << 20) | (unsigned)s2;
    }
}

__global__ void offsets_kernel(const int* __restrict__ cnt, int* __restrict__ off) {
    if (threadIdx.x == 0) {
        int s = 0;
        for (int e = 0; e < E_NUM; ++e) { off[e] = s; s += cnt[e]; }
    }
}

// ---------------- combine: out[t] = pbuf[slotA] + pbuf[slotB] ----------------
__global__ void combine_kernel(const unsigned short* __restrict__ pbuf,
                               const unsigned int* __restrict__ slot_of,
                               const int* __restrict__ off, float* __restrict__ out) {
    int t = blockIdx.x, tid = threadIdx.x;
    unsigned int a = slot_of[2 * t], b = slot_of[2 * t + 1];
    size_t ra = (size_t)(off[a >> 20] + (int)(a & 0xFFFFFu));
    size_t rb = (size_t)(off[b >> 20] + (int)(b & 0xFFFFFu));
    const unsigned short* pa = pbuf + ra * H_DIM + tid * 8;
    const unsigned short* pb = pbuf + rb * H_DIM + tid * 8;
    ushort4 a0 = *(const ushort4*)pa, a1 = *(const ushort4*)(pa + 4);
    ushort4 b0 = *(const ushort4*)pb, b1 = *(const ushort4*)(pb + 4);
    float4 r0, r1;
    r0.x = bf2f(a0.x) + bf2f(b0.x); r0.y = bf2f(a0.y) + bf2f(b0.y);
    r0.z = bf2f(a0.z) + bf2f(b0.z); r0.w = bf2f(a0.w) + bf2f(b0.w);
    r1.x = bf2f(a1.x) + bf2f(b1.x); r1.y = bf2f(a1.y) + bf2f(b1.y);
    r1.z = bf2f(a1.z) + bf2f(b1.z); r1.w = bf2f(a1.w) + bf2f(b1.w);
    float* op = out + (size_t)t * H_DIM + tid * 8;
    *(float4*)op = r0;
    *(float4*)(op + 4) = r1;
}

// ---------------- 8-phase 256x256 grouped GEMM (round-3 fused rhythm) ----------------
// Phase = {ds_read | stage-issue | setprio(1) MFMA setprio(0) | [vmcnt] | bar}.
// Extra grid blocks (bid >= gemm_grid) run an embedded f32->bf16 cvt loop
// (zero LDS, so they co-reside with the 128KB-LDS GEMM blocks and hide the
// conversion BW under GEMM compute).
template<int IS_G1>
__global__ __launch_bounds__(512, 2) void moe_gemm_kernel(
    const unsigned short* __restrict__ A_src, const unsigned short* __restrict__ W,
    const int* __restrict__ cnt, const int* __restrict__ off,
    const int* __restrict__ tok_of, const float* __restrict__ wgt_of,
    unsigned short* __restrict__ dst,
    const float* __restrict__ cvt_src, unsigned short* __restrict__ cvt_dst,
    long cvt_n, int gemm_grid, int cvt_blks) {
    if ((int)blockIdx.x >= gemm_grid) {
        // embedded converter (grid-stride)
        long i0 = ((long)((int)blockIdx.x - gemm_grid) * blockDim.x + threadIdx.x) * 4;
        long stride = (long)cvt_blks * blockDim.x * 4;
        for (long i = i0; i < cvt_n; i += stride) {
            float4 v = *(const float4*)(cvt_src + i);
            ushort4 o;
            o.x = f2bf(v.x); o.y = f2bf(v.y); o.z = f2bf(v.z); o.w = f2bf(v.w);
            *(ushort4*)(cvt_dst + i) = o;
        }
        return;
    }
    const int NT = IS_G1 ? 16 : 8;
    int bx = xcd_swizzle(blockIdx.x, gemm_grid);
    int nt = bx / (E_NUM * 32);
    int rr = bx % (E_NUM * 32);
    int e = rr / 32;
    int mt = rr % 32;
    (void)NT;
    int C = cnt[e];
    if (mt * 256 >= C) return;
    int O = off[e];

    __shared__ __align__(16) char ldsA[2][32768];
    __shared__ __align__(16) char ldsB[2][32768];

    int tid = threadIdx.x;
    int wave = tid >> 6, lane = tid & 63;
    int wr = wave >> 2, wc = wave & 3;

    // ---- staging source pointers (pre-swizzled involution) ----
    const char* aptr[4];
#pragma unroll
    for (int q = 0; q < 4; ++q) {
        int row = q * 64 + wave * 8 + (lane >> 3);
        int cu = (lane & 7) ^ (row & 7);
        int grow = mt * 256 + row; if (grow > C - 1) grow = C - 1;
        size_t arow = IS_G1 ? (size_t)tok_of[e * S_TOK + grow] : (size_t)(O + grow);
        aptr[q] = (const char*)(A_src + arow * 2048 + cu * 8);
    }
    const char* bptr[4];
#pragma unroll
    for (int j = 0; j < 4; ++j) {
        int lrow = j * 64 + wave * 8 + (lane >> 3);
        int cu = (lane & 7) ^ (lrow & 7);
        int np = lrow >> 7, wcg = (lrow >> 5) & 3, rem = lrow & 31;
        int tbrow = wcg * 64 + np * 32 + rem;
        size_t brow;
        if (IS_G1) {
            int jj = tbrow & 63, wq = tbrow >> 6;
            if (jj < 32) brow = (size_t)(nt * 128 + wq * 32 + jj);
            else         brow = (size_t)I_DIM + nt * 128 + wq * 32 + (jj - 32);
            brow += (size_t)e * (2 * I_DIM);
        } else {
            brow = (size_t)e * H_DIM + nt * 256 + tbrow;
        }
        bptr[j] = (const char*)(W + brow * 2048 + cu * 8);
    }

    // ---- swizzled ds_read byte offsets ----
    int aoff[8][2], boff[4][2];
#pragma unroll
    for (int m = 0; m < 8; ++m)
#pragma unroll
        for (int ks = 0; ks < 2; ++ks) {
            int row = wr * 128 + m * 16 + (lane & 15);
            int cu = ks * 4 + (lane >> 4);
            aoff[m][ks] = row * 128 + ((cu ^ (row & 7)) * 16);
        }
#pragma unroll
    for (int n = 0; n < 4; ++n)
#pragma unroll
        for (int ks = 0; ks < 2; ++ks) {
            int lrow = (n >> 1) * 128 + wc * 32 + (n & 1) * 16 + (lane & 15);
            int cu = ks * 4 + (lane >> 4);
            boff[n][ks] = lrow * 128 + ((cu ^ (lrow & 7)) * 16);
        }

    f32x4 acc[8][4];
#pragma unroll
    for (int m = 0; m < 8; ++m)
#pragma unroll
        for (int n = 0; n < 4; ++n)
#pragma unroll
            for (int q = 0; q < 4; ++q) acc[m][n][q] = 0.0f;

    auto gA = [&](int q, int T, int buf) {
        async_copy16(ldsA[buf] + q * 8192 + wave * 1024, aptr[q] + T * 128);
    };
    auto gB = [&](int j, int T, int buf) {
        async_copy16(ldsB[buf] + j * 8192 + wave * 1024, bptr[j] + T * 128);
    };

    // ---- prologue: A0(q0,q2,q1,q3) B0h0 A1(all) B0h1 ----
    gA(0, 0, 0); gA(2, 0, 0); gA(1, 0, 0); gA(3, 0, 0);
    gB(0, 0, 0); gB(1, 0, 0);
    gA(0, 1, 1); gA(2, 1, 1); gA(1, 1, 1); gA(3, 1, 1);
    gB(2, 0, 0); gB(3, 0, 0);
    asm volatile("s_waitcnt vmcnt(6)" ::: "memory");
    __builtin_amdgcn_s_barrier();

    bf16x8 ar[8][2], br[2][2];
    int cur = 0;
#pragma unroll 2
    for (int T = 0; T < 32; ++T) {
        int nxt = cur ^ 1;
        int TA = (T + 2 < 32) ? T + 2 : 31;
        int TB = (T + 1 < 32) ? T + 1 : 31;
        // ---- P1: rd B.np0 + A.m0-3 | gB h0(T+1) | mfma | bar ----
#pragma unroll
        for (int n = 0; n < 2; ++n)
#pragma unroll
            for (int ks = 0; ks < 2; ++ks)
                br[n][ks] = *(const bf16x8*)(ldsB[cur] + boff[n][ks]);
#pragma unroll
        for (int m = 0; m < 4; ++m)
#pragma unroll
            for (int ks = 0; ks < 2; ++ks)
                ar[m][ks] = *(const bf16x8*)(ldsA[cur] + aoff[m][ks]);
        gB(0, TB, nxt); gB(1, TB, nxt);
        __builtin_amdgcn_s_setprio(1);
#pragma unroll
        for (int m = 0; m < 4; ++m)
#pragma unroll
            for (int n = 0; n < 2; ++n) {
                acc[m][n] = MFMA16(ar[m][0], br[n][0], acc[m][n]);
                acc[m][n] = MFMA16(ar[m][1], br[n][1], acc[m][n]);
            }
        __builtin_amdgcn_s_setprio(0);
        __builtin_amdgcn_s_barrier();
        // ---- P2: rd A.m4-7 | gA q0,q2(T+2) | mfma | vmcnt(4) bar ----
#pragma unroll
        for (int m = 4; m < 8; ++m)
#pragma unroll
            for (int ks = 0; ks < 2; ++ks)
                ar[m][ks] = *(const bf16x8*)(ldsA[cur] + aoff[m][ks]);
        gA(0, TA, cur); gA(2, TA, cur);
        __builtin_amdgcn_s_setprio(1);
#pragma unroll
        for (int m = 4; m < 8; ++m)
#pragma unroll
            for (int n = 0; n < 2; ++n) {
                acc[m][n] = MFMA16(ar[m][0], br[n][0], acc[m][n]);
                acc[m][n] = MFMA16(ar[m][1], br[n][1], acc[m][n]);
            }
        __builtin_amdgcn_s_setprio(0);
        asm volatile("s_waitcnt vmcnt(4)" ::: "memory");
        __builtin_amdgcn_s_barrier();
        // ---- P3: rd B.np1 | gA q1,q3(T+2) | mfma | bar ----
#pragma unroll
        for (int n = 0; n < 2; ++n)
#pragma unroll
            for (int ks = 0; ks < 2; ++ks)
                br[n][ks] = *(const bf16x8*)(ldsB[cur] + boff[n + 2][ks]);
        gA(1, TA, cur); gA(3, TA, cur);
        __builtin_amdgcn_s_setprio(1);
#pragma unroll
        for (int m = 0; m < 4; ++m)
#pragma unroll
            for (int n = 0; n < 2; ++n) {
                acc[m][n + 2] = MFMA16(ar[m][0], br[n][0], acc[m][n + 2]);
                acc[m][n + 2] = MFMA16(ar[m][1], br[n][1], acc[m][n + 2]);
            }
        __builtin_amdgcn_s_setprio(0);
        __builtin_amdgcn_s_barrier();
        // ---- P4: gB h1(T+1) | mfma | vmcnt(6) bar ----
        gB(2, TB, nxt); gB(3, TB, nxt);
        __builtin_amdgcn_s_setprio(1);
#pragma unroll
        for (int m = 4; m < 8; ++m)
#pragma unroll
            for (int n = 0; n < 2; ++n) {
                acc[m][n + 2] = MFMA16(ar[m][0], br[n][0], acc[m][n + 2]);
                acc[m][n + 2] = MFMA16(ar[m][1], br[n][1], acc[m][n + 2]);
            }
        __builtin_amdgcn_s_setprio(0);
        asm volatile("s_waitcnt vmcnt(6)" ::: "memory");
        __builtin_amdgcn_s_barrier();
        cur = nxt;
    }

    // ---- epilogue ----
    if (IS_G1) {
#pragma unroll
        for (int m = 0; m < 8; ++m)
#pragma unroll
            for (int q = 0; q < 4; ++q) {
                int row = mt * 256 + wr * 128 + m * 16 + (lane >> 4) * 4 + q;
                if (row < C) {
                    float wgt = wgt_of[e * S_TOK + row];
                    unsigned short* hp = dst + (size_t)(O + row) * I_DIM +
                                         nt * 128 + wc * 32 + (lane & 15);
#pragma unroll
                    for (int n = 0; n < 2; ++n) {
                        float g = acc[m][n][q];
                        float u = acc[m][n + 2][q];
                        float hv = (g / (1.0f + __expf(-g))) * u * wgt;
                        hp[n * 16] = f2bf(hv);
                    }
                }
            }
    } else {
#pragma unroll
        for (int m = 0; m < 8; ++m)
#pragma unroll
            for (int q = 0; q < 4; ++q) {
                int row = mt * 256 + wr * 128 + m * 16 + (lane >> 4) * 4 + q;
                if (row < C) {
                    unsigned short* pp = dst + (size_t)(O + row) * H_DIM +
                                         nt * 256 + wc * 64 + (lane & 15);
#pragma unroll
                    for (int n = 0; n < 4; ++n)
                        pp[n * 16] = f2bf(acc[m][n][q]);
                }
            }
    }
}

extern "C" void kernel_launch(void* const* d_in, const int* in_sizes, int n_in,
                              void* d_out, int out_size, void* d_ws, size_t ws_size,
                              hipStream_t stream) {
    const float* hs = (const float*)d_in[0];
    const float* wg = (const float*)d_in[1];
    const float* w1 = (const float*)d_in[2];
    const float* w2 = (const float*)d_in[3];

    float* out = (float*)d_out;
    float* logits = out + (size_t)S_TOK * H_DIM;

    char* ws = (char*)d_ws;
    int* cnt = (int*)ws;
    int* off = (int*)(ws + 256);
    int* tok_of = (int*)(ws + 512);
    float* wgt_of = (float*)(ws + 512 + (size_t)E_NUM * S_TOK * 4);
    unsigned int* slot_of = (unsigned int*)(ws + 512 + (size_t)E_NUM * S_TOK * 8);
    size_t o = 512 + (size_t)E_NUM * S_TOK * 8 + (size_t)S_TOK * 8;
    o = (o + 4095) & ~(size_t)4095;
    unsigned short* hsb = (unsigned short*)(ws + o);  o += (size_t)S_TOK * H_DIM * 2;             // 32 MiB
    unsigned short* wxb = (unsigned short*)(ws + o);  o += (size_t)E_NUM * 2 * I_DIM * H_DIM * 2; // 128 MiB (w1)
    unsigned short* hbuf = (unsigned short*)(ws + o); o += (size_t)S_TOK * 2 * I_DIM * 2;         // 64 MiB
    size_t o_w2 = o;                                  // optional separate 64 MiB w2 region
    size_t need_fused = o_w2 + (size_t)E_NUM * H_DIM * I_DIM * 2;
    bool fused = (ws_size >= need_fused);

    const long W1_N = (long)E_NUM * 2 * I_DIM * H_DIM;
    const long W2_N = (long)E_NUM * H_DIM * I_DIM;
    const int G1_GRID = E_NUM * 32 * 16;  // 4096
    const int G2_GRID = E_NUM * 32 * 8;   // 2048
    const int CVT_BLKS = 1024;

    hipMemsetAsync(cnt, 0, 64, stream);
    router_kernel<<<S_TOK, 256, 0, stream>>>(hs, wg, logits, cnt, tok_of, wgt_of, slot_of, hsb);
    offsets_kernel<<<1, 64, 0, stream>>>(cnt, off);
    cvt_kernel<<<4096, 256, 0, stream>>>(w1, wxb, W1_N);

    if (fused) {
        unsigned short* w2b = (unsigned short*)(ws + o_w2);
        unsigned short* pbuf = wxb;  // w1 dead after gemm1
        // gemm1 + concurrent w2 conversion (separate region: no hazard)
        moe_gemm_kernel<1><<<G1_GRID + CVT_BLKS, 512, 0, stream>>>(
            hsb, wxb, cnt, off, tok_of, wgt_of, hbuf, w2, w2b, W2_N, G1_GRID, CVT_BLKS);
        moe_gemm_kernel<0><<<G2_GRID, 512, 0, stream>>>(
            hbuf, w2b, cnt, off, tok_of, wgt_of, pbuf, nullptr, nullptr, 0, G2_GRID, 0);
        combine_kernel<<<S_TOK, 256, 0, stream>>>(pbuf, slot_of, off, out);
    } else {
        // sequential fallback: w2 overwrites w1's lower half; partials in upper half
        unsigned short* w2b = wxb;
        unsigned short* pbuf = wxb + (size_t)E_NUM * H_DIM * I_DIM;
        moe_gemm_kernel<1><<<G1_GRID, 512, 0, stream>>>(
            hsb, wxb, cnt, off, tok_of, wgt_of, hbuf, nullptr, nullptr, 0, G1_GRID, 0);
        cvt_kernel<<<4096, 256, 0, stream>>>(w2, w2b, W2_N);
        moe_gemm_kernel<0><<<G2_GRID, 512, 0, stream>>>(
            hbuf, w2b, cnt, off, tok_of, wgt_of, pbuf, nullptr, nullptr, 0, G2_GRID, 0);
        combine_kernel<<<S_TOK, 256, 0, stream>>>(pbuf, slot_of, off, out);
    }
}

// Round 6
// 738.698 us; speedup vs baseline: 1.9147x; 1.0204x over previous
//
#include <hip/hip_runtime.h>
#include <hip/hip_bf16.h>
#include <stdint.h>

#define S_TOK 8192
#define H_DIM 2048
#define I_DIM 2048
#define E_NUM 8

typedef __attribute__((ext_vector_type(4))) float f32x4;
typedef __attribute__((ext_vector_type(8))) short bf16x8;
typedef __attribute__((ext_vector_type(8))) unsigned short u16x8;

#define MFMA16(a, b, c) __builtin_amdgcn_mfma_f32_16x16x32_bf16((a), (b), (c), 0, 0, 0)

// f32 -> bf16 RNE
__device__ __forceinline__ unsigned short f2bf(float f) {
    unsigned int u = __float_as_uint(f);
    unsigned int r = (u + 0x7FFFu + ((u >> 16) & 1u)) >> 16;
    return (unsigned short)r;
}
__device__ __forceinline__ float bf2f(unsigned short u) {
    return __uint_as_float((unsigned int)u << 16);
}

__device__ __forceinline__ void cvt8(const float* __restrict__ s, unsigned short* __restrict__ d) {
    float4 v0 = *(const float4*)s;
    float4 v1 = *(const float4*)(s + 4);
    u16x8 o;
    o[0] = f2bf(v0.x); o[1] = f2bf(v0.y); o[2] = f2bf(v0.z); o[3] = f2bf(v0.w);
    o[4] = f2bf(v1.x); o[5] = f2bf(v1.y); o[6] = f2bf(v1.z); o[7] = f2bf(v1.w);
    *(u16x8*)d = o;
}

// async global->LDS, 16B per lane. LDS dest is wave-uniform base + lane*16.
__device__ __forceinline__ void async_copy16(void* lds, const void* g) {
    __builtin_amdgcn_global_load_lds(
        (const __attribute__((address_space(1))) void*)(uintptr_t)g,
        (__attribute__((address_space(3))) void*)(uintptr_t)lds,
        16, 0, 0);
}

// XCD-aware block swizzle (nwg % 8 == 0 for all our grids)
__device__ __forceinline__ int xcd_swizzle(int bid, int nwg) {
    int cpx = nwg >> 3;
    return (bid & 7) * cpx + (bid >> 3);
}

// ---------------- flat f32 -> bf16 conversion ----------------
__global__ void cvt_kernel(const float* __restrict__ src, unsigned short* __restrict__ dst, long n) {
    long i0 = ((long)blockIdx.x * blockDim.x + threadIdx.x) * 8;
    long stride = (long)gridDim.x * blockDim.x * 8;
    for (long i = i0; i < n; i += stride) cvt8(src + i, dst + i);
}

// ---------------- w1 half conversion ----------------
// w1[e] flat = 4*CH elements: gate=[0,2CH), up=[2CH,4CH). HALF=0 converts
// gate-lo [0,CH) + up-lo [2CH,3CH) (rows [0,1024) of each) -> needed by nt<8.
// HALF=1 converts gate-hi + up-hi (rows [1024,2048)) -> needed by nt>=8.
template<int HALF>
__device__ __forceinline__ void cvt_w1_half_body(const float* __restrict__ src,
                                                 unsigned short* __restrict__ dst,
                                                 long i0, long stride) {
    const long CH = 1L << 21;                 // 1024*2048
    const long TOT = (long)E_NUM * 2 * CH;    // 16.8M
    for (long j = i0; j < TOT; j += stride) {
        long e = j >> 22;
        long piece = (j >> 21) & 1;
        long off = j & (CH - 1);
        long g = (e << 23) + ((piece * 2 + HALF) << 21) + off;
        cvt8(src + g, dst + g);
    }
}

template<int HALF>
__global__ void cvt_w1_half_kernel(const float* __restrict__ src, unsigned short* __restrict__ dst) {
    long i0 = ((long)blockIdx.x * blockDim.x + threadIdx.x) * 8;
    long stride = (long)gridDim.x * blockDim.x * 8;
    cvt_w1_half_body<HALF>(src, dst, i0, stride);
}

// ---------------- router: logits (f32 exact), top-2, lists, hs->bf16 ----------------
__global__ void router_kernel(const float* __restrict__ hs, const float* __restrict__ wg,
                              float* __restrict__ logits, int* __restrict__ cnt,
                              int* __restrict__ tok_of, float* __restrict__ wgt_of,
                              unsigned int* __restrict__ slot_of,
                              unsigned short* __restrict__ hsb) {
    int t = blockIdx.x;
    int tid = threadIdx.x;
    const float* hrow = hs + (size_t)t * H_DIM;
    float4 h0 = *(const float4*)(hrow + tid * 8);
    float4 h1 = *(const float4*)(hrow + tid * 8 + 4);
    u16x8 o;
    o[0] = f2bf(h0.x); o[1] = f2bf(h0.y); o[2] = f2bf(h0.z); o[3] = f2bf(h0.w);
    o[4] = f2bf(h1.x); o[5] = f2bf(h1.y); o[6] = f2bf(h1.z); o[7] = f2bf(h1.w);
    *(u16x8*)(hsb + (size_t)t * H_DIM + tid * 8) = o;

    float p[E_NUM];
#pragma unroll
    for (int e = 0; e < E_NUM; ++e) {
        const float* w = wg + (size_t)e * H_DIM + tid * 8;
        float4 w0 = *(const float4*)(w);
        float4 w1v = *(const float4*)(w + 4);
        p[e] = h0.x * w0.x + h0.y * w0.y + h0.z * w0.z + h0.w * w0.w +
               h1.x * w1v.x + h1.y * w1v.y + h1.z * w1v.z + h1.w * w1v.w;
    }
#pragma unroll
    for (int e = 0; e < E_NUM; ++e)
#pragma unroll
        for (int d = 32; d > 0; d >>= 1) p[e] += __shfl_xor(p[e], d, 64);

    __shared__ float red[4][E_NUM];
    int wave = tid >> 6, lane = tid & 63;
    if (lane == 0) {
#pragma unroll
        for (int e = 0; e < E_NUM; ++e) red[wave][e] = p[e];
    }
    __syncthreads();
    if (tid == 0) {
        float l[E_NUM];
#pragma unroll
        for (int e = 0; e < E_NUM; ++e) l[e] = red[0][e] + red[1][e] + red[2][e] + red[3][e];
#pragma unroll
        for (int e = 0; e < E_NUM; ++e) logits[(size_t)t * E_NUM + e] = l[e];
        int i1 = 0;
#pragma unroll
        for (int e = 1; e < E_NUM; ++e) if (l[e] > l[i1]) i1 = e;
        int i2 = (i1 == 0) ? 1 : 0;
#pragma unroll
        for (int e = 0; e < E_NUM; ++e) if (e != i1 && l[e] > l[i2]) i2 = e;
        float b = __expf(l[i2] - l[i1]);
        float wA = 1.0f / (1.0f + b);
        float wB = 1.0f - wA;
        int s1 = atomicAdd(&cnt[i1], 1);
        tok_of[i1 * S_TOK + s1] = t; wgt_of[i1 * S_TOK + s1] = wA;
        int s2 = atomicAdd(&cnt[i2], 1);
        tok_of[i2 * S_TOK + s2] = t; wgt_of[i2 * S_TOK + s2] = wB;
        slot_of[2 * t]     = ((unsigned)i1 << 20) | (unsigned)s1;
        slot_of[2 * t + 1] = ((unsigned)i2 << 20) | (unsigned)s2;
    }
}

__global__ void offsets_kernel(const int* __restrict__ cnt, int* __restrict__ off) {
    if (threadIdx.x == 0) {
        int s = 0;
        for (int e = 0; e < E_NUM; ++e) { off[e] = s; s += cnt[e]; }
    }
}

// ---------------- combine: out[t] = pbuf[slotA] + pbuf[slotB] ----------------
__global__ void combine_kernel(const unsigned short* __restrict__ pbuf,
                               const unsigned int* __restrict__ slot_of,
                               const int* __restrict__ off, float* __restrict__ out) {
    int t = blockIdx.x, tid = threadIdx.x;
    unsigned int a = slot_of[2 * t], b = slot_of[2 * t + 1];
    size_t ra = (size_t)(off[a >> 20] + (int)(a & 0xFFFFFu));
    size_t rb = (size_t)(off[b >> 20] + (int)(b & 0xFFFFFu));
    const unsigned short* pa = pbuf + ra * H_DIM + tid * 8;
    const unsigned short* pb = pbuf + rb * H_DIM + tid * 8;
    ushort4 a0 = *(const ushort4*)pa, a1 = *(const ushort4*)(pa + 4);
    ushort4 b0 = *(const ushort4*)pb, b1 = *(const ushort4*)(pb + 4);
    float4 r0, r1;
    r0.x = bf2f(a0.x) + bf2f(b0.x); r0.y = bf2f(a0.y) + bf2f(b0.y);
    r0.z = bf2f(a0.z) + bf2f(b0.z); r0.w = bf2f(a0.w) + bf2f(b0.w);
    r1.x = bf2f(a1.x) + bf2f(b1.x); r1.y = bf2f(a1.y) + bf2f(b1.y);
    r1.z = bf2f(a1.z) + bf2f(b1.z); r1.w = bf2f(a1.w) + bf2f(b1.w);
    float* op = out + (size_t)t * H_DIM + tid * 8;
    *(float4*)op = r0;
    *(float4*)(op + 4) = r1;
}

// ---------------- 8-phase 256x256 grouped GEMM (round-3 fused rhythm) ----------------
// Phase = {ds_read | stage-issue | setprio(1) MFMA setprio(0) | [vmcnt] | bar}.
// Blocks with bid >= gemm_grid run an embedded cvt loop instead
// (cvt_mode 1 = flat, 2 = w1 half-1). They time-share CUs with GEMM blocks.
template<int IS_G1>
__global__ __launch_bounds__(512, 2) void moe_gemm_kernel(
    const unsigned short* __restrict__ A_src, const unsigned short* __restrict__ W,
    const int* __restrict__ cnt, const int* __restrict__ off,
    const int* __restrict__ tok_of, const float* __restrict__ wgt_of,
    unsigned short* __restrict__ dst,
    const float* __restrict__ cvt_src, unsigned short* __restrict__ cvt_dst,
    long cvt_n, int gemm_grid, int cvt_blks, int nt_base, int cvt_mode) {
    if ((int)blockIdx.x >= gemm_grid) {
        long i0 = ((long)((int)blockIdx.x - gemm_grid) * blockDim.x + threadIdx.x) * 8;
        long stride = (long)cvt_blks * blockDim.x * 8;
        if (cvt_mode == 2) {
            cvt_w1_half_body<1>(cvt_src, cvt_dst, i0, stride);
        } else {
            for (long i = i0; i < cvt_n; i += stride) cvt8(cvt_src + i, cvt_dst + i);
        }
        return;
    }
    int bx = xcd_swizzle(blockIdx.x, gemm_grid);
    int nt = nt_base + bx / (E_NUM * 32);
    int rr = bx % (E_NUM * 32);
    int e = rr / 32;
    int mt = rr % 32;
    int C = cnt[e];
    if (mt * 256 >= C) return;
    int O = off[e];

    __shared__ __align__(16) char ldsA[2][32768];
    __shared__ __align__(16) char ldsB[2][32768];

    int tid = threadIdx.x;
    int wave = tid >> 6, lane = tid & 63;
    int wr = wave >> 2, wc = wave & 3;

    // ---- staging source pointers (pre-swizzled involution) ----
    const char* aptr[4];
#pragma unroll
    for (int q = 0; q < 4; ++q) {
        int row = q * 64 + wave * 8 + (lane >> 3);
        int cu = (lane & 7) ^ (row & 7);
        int grow = mt * 256 + row; if (grow > C - 1) grow = C - 1;
        size_t arow = IS_G1 ? (size_t)tok_of[e * S_TOK + grow] : (size_t)(O + grow);
        aptr[q] = (const char*)(A_src + arow * 2048 + cu * 8);
    }
    const char* bptr[4];
#pragma unroll
    for (int j = 0; j < 4; ++j) {
        int lrow = j * 64 + wave * 8 + (lane >> 3);
        int cu = (lane & 7) ^ (lrow & 7);
        int np = lrow >> 7, wcg = (lrow >> 5) & 3, rem = lrow & 31;
        int tbrow = wcg * 64 + np * 32 + rem;
        size_t brow;
        if (IS_G1) {
            int jj = tbrow & 63, wq = tbrow >> 6;
            if (jj < 32) brow = (size_t)(nt * 128 + wq * 32 + jj);
            else         brow = (size_t)I_DIM + nt * 128 + wq * 32 + (jj - 32);
            brow += (size_t)e * (2 * I_DIM);
        } else {
            brow = (size_t)e * H_DIM + nt * 256 + tbrow;
        }
        bptr[j] = (const char*)(W + brow * 2048 + cu * 8);
    }

    // ---- swizzled ds_read byte offsets ----
    int aoff[8][2], boff[4][2];
#pragma unroll
    for (int m = 0; m < 8; ++m)
#pragma unroll
        for (int ks = 0; ks < 2; ++ks) {
            int row = wr * 128 + m * 16 + (lane & 15);
            int cu = ks * 4 + (lane >> 4);
            aoff[m][ks] = row * 128 + ((cu ^ (row & 7)) * 16);
        }
#pragma unroll
    for (int n = 0; n < 4; ++n)
#pragma unroll
        for (int ks = 0; ks < 2; ++ks) {
            int lrow = (n >> 1) * 128 + wc * 32 + (n & 1) * 16 + (lane & 15);
            int cu = ks * 4 + (lane >> 4);
            boff[n][ks] = lrow * 128 + ((cu ^ (lrow & 7)) * 16);
        }

    f32x4 acc[8][4];
#pragma unroll
    for (int m = 0; m < 8; ++m)
#pragma unroll
        for (int n = 0; n < 4; ++n)
#pragma unroll
            for (int q = 0; q < 4; ++q) acc[m][n][q] = 0.0f;

    auto gA = [&](int q, int T, int buf) {
        async_copy16(ldsA[buf] + q * 8192 + wave * 1024, aptr[q] + T * 128);
    };
    auto gB = [&](int j, int T, int buf) {
        async_copy16(ldsB[buf] + j * 8192 + wave * 1024, bptr[j] + T * 128);
    };

    // ---- prologue ----
    gA(0, 0, 0); gA(2, 0, 0); gA(1, 0, 0); gA(3, 0, 0);
    gB(0, 0, 0); gB(1, 0, 0);
    gA(0, 1, 1); gA(2, 1, 1); gA(1, 1, 1); gA(3, 1, 1);
    gB(2, 0, 0); gB(3, 0, 0);
    asm volatile("s_waitcnt vmcnt(6)" ::: "memory");
    __builtin_amdgcn_s_barrier();

    bf16x8 ar[8][2], br[2][2];
    int cur = 0;
#pragma unroll 2
    for (int T = 0; T < 32; ++T) {
        int nxt = cur ^ 1;
        int TA = (T + 2 < 32) ? T + 2 : 31;
        int TB = (T + 1 < 32) ? T + 1 : 31;
        // ---- P1 ----
#pragma unroll
        for (int n = 0; n < 2; ++n)
#pragma unroll
            for (int ks = 0; ks < 2; ++ks)
                br[n][ks] = *(const bf16x8*)(ldsB[cur] + boff[n][ks]);
#pragma unroll
        for (int m = 0; m < 4; ++m)
#pragma unroll
            for (int ks = 0; ks < 2; ++ks)
                ar[m][ks] = *(const bf16x8*)(ldsA[cur] + aoff[m][ks]);
        gB(0, TB, nxt); gB(1, TB, nxt);
        __builtin_amdgcn_s_setprio(1);
#pragma unroll
        for (int m = 0; m < 4; ++m)
#pragma unroll
            for (int n = 0; n < 2; ++n) {
                acc[m][n] = MFMA16(ar[m][0], br[n][0], acc[m][n]);
                acc[m][n] = MFMA16(ar[m][1], br[n][1], acc[m][n]);
            }
        __builtin_amdgcn_s_setprio(0);
        __builtin_amdgcn_s_barrier();
        // ---- P2 ----
#pragma unroll
        for (int m = 4; m < 8; ++m)
#pragma unroll
            for (int ks = 0; ks < 2; ++ks)
                ar[m][ks] = *(const bf16x8*)(ldsA[cur] + aoff[m][ks]);
        gA(0, TA, cur); gA(2, TA, cur);
        __builtin_amdgcn_s_setprio(1);
#pragma unroll
        for (int m = 4; m < 8; ++m)
#pragma unroll
            for (int n = 0; n < 2; ++n) {
                acc[m][n] = MFMA16(ar[m][0], br[n][0], acc[m][n]);
                acc[m][n] = MFMA16(ar[m][1], br[n][1], acc[m][n]);
            }
        __builtin_amdgcn_s_setprio(0);
        asm volatile("s_waitcnt vmcnt(4)" ::: "memory");
        __builtin_amdgcn_s_barrier();
        // ---- P3 ----
#pragma unroll
        for (int n = 0; n < 2; ++n)
#pragma unroll
            for (int ks = 0; ks < 2; ++ks)
                br[n][ks] = *(const bf16x8*)(ldsB[cur] + boff[n + 2][ks]);
        gA(1, TA, cur); gA(3, TA, cur);
        __builtin_amdgcn_s_setprio(1);
#pragma unroll
        for (int m = 0; m < 4; ++m)
#pragma unroll
            for (int n = 0; n < 2; ++n) {
                acc[m][n + 2] = MFMA16(ar[m][0], br[n][0], acc[m][n + 2]);
                acc[m][n + 2] = MFMA16(ar[m][1], br[n][1], acc[m][n + 2]);
            }
        __builtin_amdgcn_s_setprio(0);
        __builtin_amdgcn_s_barrier();
        // ---- P4 ----
        gB(2, TB, nxt); gB(3, TB, nxt);
        __builtin_amdgcn_s_setprio(1);
#pragma unroll
        for (int m = 4; m < 8; ++m)
#pragma unroll
            for (int n = 0; n < 2; ++n) {
                acc[m][n + 2] = MFMA16(ar[m][0], br[n][0], acc[m][n + 2]);
                acc[m][n + 2] = MFMA16(ar[m][1], br[n][1], acc[m][n + 2]);
            }
        __builtin_amdgcn_s_setprio(0);
        asm volatile("s_waitcnt vmcnt(6)" ::: "memory");
        __builtin_amdgcn_s_barrier();
        cur = nxt;
    }

    // ---- epilogue ----
    if (IS_G1) {
#pragma unroll
        for (int m = 0; m < 8; ++m)
#pragma unroll
            for (int q = 0; q < 4; ++q) {
                int row = mt * 256 + wr * 128 + m * 16 + (lane >> 4) * 4 + q;
                if (row < C) {
                    float wgt = wgt_of[e * S_TOK + row];
                    unsigned short* hp = dst + (size_t)(O + row) * I_DIM +
                                         nt * 128 + wc * 32 + (lane & 15);
#pragma unroll
                    for (int n = 0; n < 2; ++n) {
                        float g = acc[m][n][q];
                        float u = acc[m][n + 2][q];
                        float hv = (g / (1.0f + __expf(-g))) * u * wgt;
                        hp[n * 16] = f2bf(hv);
                    }
                }
            }
    } else {
#pragma unroll
        for (int m = 0; m < 8; ++m)
#pragma unroll
            for (int q = 0; q < 4; ++q) {
                int row = mt * 256 + wr * 128 + m * 16 + (lane >> 4) * 4 + q;
                if (row < C) {
                    unsigned short* pp = dst + (size_t)(O + row) * H_DIM +
                                         nt * 256 + wc * 64 + (lane & 15);
#pragma unroll
                    for (int n = 0; n < 4; ++n)
                        pp[n * 16] = f2bf(acc[m][n][q]);
                }
            }
    }
}

extern "C" void kernel_launch(void* const* d_in, const int* in_sizes, int n_in,
                              void* d_out, int out_size, void* d_ws, size_t ws_size,
                              hipStream_t stream) {
    const float* hs = (const float*)d_in[0];
    const float* wg = (const float*)d_in[1];
    const float* w1 = (const float*)d_in[2];
    const float* w2 = (const float*)d_in[3];

    float* out = (float*)d_out;
    float* logits = out + (size_t)S_TOK * H_DIM;

    char* ws = (char*)d_ws;
    int* cnt = (int*)ws;
    int* off = (int*)(ws + 256);
    int* tok_of = (int*)(ws + 512);
    float* wgt_of = (float*)(ws + 512 + (size_t)E_NUM * S_TOK * 4);
    unsigned int* slot_of = (unsigned int*)(ws + 512 + (size_t)E_NUM * S_TOK * 8);
    size_t o = 512 + (size_t)E_NUM * S_TOK * 8 + (size_t)S_TOK * 8;
    o = (o + 4095) & ~(size_t)4095;
    unsigned short* hsb = (unsigned short*)(ws + o);  o += (size_t)S_TOK * H_DIM * 2;             // 32 MiB
    unsigned short* wxb = (unsigned short*)(ws + o);  o += (size_t)E_NUM * 2 * I_DIM * H_DIM * 2; // 128 MiB (w1)
    unsigned short* hbuf = (unsigned short*)(ws + o); o += (size_t)S_TOK * 2 * I_DIM * 2;         // 64 MiB
    size_t o_w2 = o;                                  // separate 64 MiB w2 region (fused mode)
    size_t need_fused = o_w2 + (size_t)E_NUM * H_DIM * I_DIM * 2;
    bool fused = (ws_size >= need_fused);

    const long W1_N = (long)E_NUM * 2 * I_DIM * H_DIM;
    const long W2_N = (long)E_NUM * H_DIM * I_DIM;
    const int G1H_GRID = E_NUM * 32 * 8;  // 2048 (half of gemm1's nt range)
    const int G2_GRID = E_NUM * 32 * 8;   // 2048
    const int CVT_BLKS = 1024;

    hipMemsetAsync(cnt, 0, 64, stream);
    router_kernel<<<S_TOK, 256, 0, stream>>>(hs, wg, logits, cnt, tok_of, wgt_of, slot_of, hsb);
    offsets_kernel<<<1, 64, 0, stream>>>(cnt, off);

    if (fused) {
        unsigned short* w2b = (unsigned short*)(ws + o_w2);
        unsigned short* pbuf = wxb;  // w1 dead after gemm1b
        // serial: convert only the w1 half gemm1a needs (~100 MB traffic)
        cvt_w1_half_kernel<0><<<4096, 256, 0, stream>>>(w1, wxb);
        // gemm1a (nt 0-7) + embedded cvt of w1's other half
        moe_gemm_kernel<1><<<G1H_GRID + CVT_BLKS, 512, 0, stream>>>(
            hsb, wxb, cnt, off, tok_of, wgt_of, hbuf,
            w1, wxb, 0, G1H_GRID, CVT_BLKS, 0, 2);
        // gemm1b (nt 8-15) + embedded cvt of w2
        moe_gemm_kernel<1><<<G1H_GRID + CVT_BLKS, 512, 0, stream>>>(
            hsb, wxb, cnt, off, tok_of, wgt_of, hbuf,
            w2, w2b, W2_N, G1H_GRID, CVT_BLKS, 8, 1);
        moe_gemm_kernel<0><<<G2_GRID, 512, 0, stream>>>(
            hbuf, w2b, cnt, off, tok_of, wgt_of, pbuf,
            nullptr, nullptr, 0, G2_GRID, 0, 0, 0);
        combine_kernel<<<S_TOK, 256, 0, stream>>>(pbuf, slot_of, off, out);
    } else {
        // sequential fallback
        unsigned short* w2b = wxb;
        unsigned short* pbuf = wxb + (size_t)E_NUM * H_DIM * I_DIM;
        cvt_kernel<<<4096, 256, 0, stream>>>(w1, wxb, W1_N);
        moe_gemm_kernel<1><<<E_NUM * 32 * 16, 512, 0, stream>>>(
            hsb, wxb, cnt, off, tok_of, wgt_of, hbuf,
            nullptr, nullptr, 0, E_NUM * 32 * 16, 0, 0, 0);
        cvt_kernel<<<4096, 256, 0, stream>>>(w2, w2b, W2_N);
        moe_gemm_kernel<0><<<G2_GRID, 512, 0, stream>>>(
            hbuf, w2b, cnt, off, tok_of, wgt_of, pbuf,
            nullptr, nullptr, 0, G2_GRID, 0, 0, 0);
        combine_kernel<<<S_TOK, 256, 0, stream>>>(pbuf, slot_of, off, out);
    }
}

// Round 7
// 607.321 us; speedup vs baseline: 2.3289x; 1.2163x over previous
//
#include <hip/hip_runtime.h>
#include <hip/hip_bf16.h>
#include <stdint.h>

#define S_TOK 8192
#define H_DIM 2048
#define I_DIM 2048
#define E_NUM 8

typedef __attribute__((ext_vector_type(4))) float f32x4;
typedef __attribute__((ext_vector_type(8))) short bf16x8;
typedef __attribute__((ext_vector_type(8))) unsigned short u16x8;

#define MFMA16(a, b, c) __builtin_amdgcn_mfma_f32_16x16x32_bf16((a), (b), (c), 0, 0, 0)

// f32 -> bf16 RNE
__device__ __forceinline__ unsigned short f2bf(float f) {
    unsigned int u = __float_as_uint(f);
    unsigned int r = (u + 0x7FFFu + ((u >> 16) & 1u)) >> 16;
    return (unsigned short)r;
}
__device__ __forceinline__ float bf2f(unsigned short u) {
    return __uint_as_float((unsigned int)u << 16);
}

__device__ __forceinline__ void cvt8(const float* __restrict__ s, unsigned short* __restrict__ d) {
    float4 v0 = *(const float4*)s;
    float4 v1 = *(const float4*)(s + 4);
    u16x8 o;
    o[0] = f2bf(v0.x); o[1] = f2bf(v0.y); o[2] = f2bf(v0.z); o[3] = f2bf(v0.w);
    o[4] = f2bf(v1.x); o[5] = f2bf(v1.y); o[6] = f2bf(v1.z); o[7] = f2bf(v1.w);
    *(u16x8*)d = o;
}

// async global->LDS, 16B per lane. LDS dest is wave-uniform base + lane*16.
__device__ __forceinline__ void async_copy16(void* lds, const void* g) {
    __builtin_amdgcn_global_load_lds(
        (const __attribute__((address_space(1))) void*)(uintptr_t)g,
        (__attribute__((address_space(3))) void*)(uintptr_t)lds,
        16, 0, 0);
}

// XCD-aware block swizzle (nwg % 8 == 0 for all our grids)
__device__ __forceinline__ int xcd_swizzle(int bid, int nwg) {
    int cpx = nwg >> 3;
    return (bid & 7) * cpx + (bid >> 3);
}

// ---------------- flat f32 -> bf16 conversion ----------------
__global__ void cvt_kernel(const float* __restrict__ src, unsigned short* __restrict__ dst, long n) {
    long i0 = ((long)blockIdx.x * blockDim.x + threadIdx.x) * 8;
    long stride = (long)gridDim.x * blockDim.x * 8;
    for (long i = i0; i < n; i += stride) cvt8(src + i, dst + i);
}

// ---------------- w1 half conversion ----------------
// HALF=0: gate rows [0,1024) + up rows [0,1024) per expert (needed by nt<8).
// HALF=1: gate/up rows [1024,2048) (needed by nt>=8).
template<int HALF>
__device__ __forceinline__ void cvt_w1_half_body(const float* __restrict__ src,
                                                 unsigned short* __restrict__ dst,
                                                 long i0, long stride) {
    const long CH = 1L << 21;                 // 1024*2048
    const long TOT = (long)E_NUM * 2 * CH;    // 16.8M
    for (long j = i0; j < TOT; j += stride) {
        long e = j >> 22;
        long piece = (j >> 21) & 1;
        long off = j & (CH - 1);
        long g = (e << 23) + ((piece * 2 + HALF) << 21) + off;
        cvt8(src + g, dst + g);
    }
}

template<int HALF>
__global__ void cvt_w1_half_kernel(const float* __restrict__ src, unsigned short* __restrict__ dst) {
    long i0 = ((long)blockIdx.x * blockDim.x + threadIdx.x) * 8;
    long stride = (long)gridDim.x * blockDim.x * 8;
    cvt_w1_half_body<HALF>(src, dst, i0, stride);
}

// ---------------- router: logits (f32 exact), top-2 choice, hs->bf16 ----------------
// NO atomics: slot assignment moved to scan_kernel (deterministic, token order).
__global__ void router_kernel(const float* __restrict__ hs, const float* __restrict__ wg,
                              float* __restrict__ logits,
                              unsigned int* __restrict__ tchoice, float* __restrict__ twgt,
                              unsigned short* __restrict__ hsb) {
    int t = blockIdx.x;
    int tid = threadIdx.x;
    const float* hrow = hs + (size_t)t * H_DIM;
    float4 h0 = *(const float4*)(hrow + tid * 8);
    float4 h1 = *(const float4*)(hrow + tid * 8 + 4);
    u16x8 o;
    o[0] = f2bf(h0.x); o[1] = f2bf(h0.y); o[2] = f2bf(h0.z); o[3] = f2bf(h0.w);
    o[4] = f2bf(h1.x); o[5] = f2bf(h1.y); o[6] = f2bf(h1.z); o[7] = f2bf(h1.w);
    *(u16x8*)(hsb + (size_t)t * H_DIM + tid * 8) = o;

    float p[E_NUM];
#pragma unroll
    for (int e = 0; e < E_NUM; ++e) {
        const float* w = wg + (size_t)e * H_DIM + tid * 8;
        float4 w0 = *(const float4*)(w);
        float4 w1v = *(const float4*)(w + 4);
        p[e] = h0.x * w0.x + h0.y * w0.y + h0.z * w0.z + h0.w * w0.w +
               h1.x * w1v.x + h1.y * w1v.y + h1.z * w1v.z + h1.w * w1v.w;
    }
#pragma unroll
    for (int e = 0; e < E_NUM; ++e)
#pragma unroll
        for (int d = 32; d > 0; d >>= 1) p[e] += __shfl_xor(p[e], d, 64);

    __shared__ float red[4][E_NUM];
    int wave = tid >> 6, lane = tid & 63;
    if (lane == 0) {
#pragma unroll
        for (int e = 0; e < E_NUM; ++e) red[wave][e] = p[e];
    }
    __syncthreads();
    if (tid == 0) {
        float l[E_NUM];
#pragma unroll
        for (int e = 0; e < E_NUM; ++e) l[e] = red[0][e] + red[1][e] + red[2][e] + red[3][e];
#pragma unroll
        for (int e = 0; e < E_NUM; ++e) logits[(size_t)t * E_NUM + e] = l[e];
        int i1 = 0;
#pragma unroll
        for (int e = 1; e < E_NUM; ++e) if (l[e] > l[i1]) i1 = e;
        int i2 = (i1 == 0) ? 1 : 0;
#pragma unroll
        for (int e = 0; e < E_NUM; ++e) if (e != i1 && l[e] > l[i2]) i2 = e;
        float b = __expf(l[i2] - l[i1]);
        tchoice[t] = (unsigned)i1 | ((unsigned)i2 << 4);
        twgt[t] = 1.0f / (1.0f + b);
    }
}

// ---------------- scan: deterministic slot assignment (token order) ----------------
// 1 block x 1024 threads; thread t owns tokens [8t, 8t+8).
__global__ __launch_bounds__(1024) void scan_kernel(
    const unsigned int* __restrict__ tchoice, const float* __restrict__ twgt,
    int* __restrict__ cnt, int* __restrict__ off,
    int* __restrict__ tok_of, float* __restrict__ wgt_of,
    unsigned int* __restrict__ slot_of) {
    __shared__ int lcnt[E_NUM][1024];
    __shared__ int tot[E_NUM];
    int tid = threadIdx.x;
    unsigned int ch[8];
    int c[E_NUM];
#pragma unroll
    for (int e = 0; e < E_NUM; ++e) c[e] = 0;
#pragma unroll
    for (int k = 0; k < 8; ++k) {
        ch[k] = tchoice[tid * 8 + k];
        c[ch[k] & 15]++;
        c[(ch[k] >> 4) & 15]++;
    }
#pragma unroll
    for (int e = 0; e < E_NUM; ++e) lcnt[e][tid] = c[e];
    __syncthreads();
    int wave = tid >> 6, lane = tid & 63;
    if (wave < E_NUM) {
        int base = 0;
        for (int chk = 0; chk < 16; ++chk) {
            int v = lcnt[wave][chk * 64 + lane];
            int inc = v;
#pragma unroll
            for (int d = 1; d < 64; d <<= 1) {
                int u = __shfl_up(inc, d, 64);
                if (lane >= d) inc += u;
            }
            lcnt[wave][chk * 64 + lane] = base + inc - v;  // exclusive prefix
            base += __shfl(inc, 63, 64);
        }
        if (lane == 0) tot[wave] = base;
    }
    __syncthreads();
    if (tid == 0) {
        int s = 0;
#pragma unroll
        for (int e = 0; e < E_NUM; ++e) { off[e] = s; cnt[e] = tot[e]; s += tot[e]; }
    }
    __syncthreads();
#pragma unroll
    for (int e = 0; e < E_NUM; ++e) c[e] = lcnt[e][tid];
#pragma unroll
    for (int k = 0; k < 8; ++k) {
        int t = tid * 8 + k;
        int i1 = ch[k] & 15, i2 = (ch[k] >> 4) & 15;
        float wA = twgt[t];
        int s1 = c[i1]++;
        int s2 = c[i2]++;
        tok_of[i1 * S_TOK + s1] = t; wgt_of[i1 * S_TOK + s1] = wA;
        tok_of[i2 * S_TOK + s2] = t; wgt_of[i2 * S_TOK + s2] = 1.0f - wA;
        slot_of[2 * t]     = ((unsigned)i1 << 20) | (unsigned)s1;
        slot_of[2 * t + 1] = ((unsigned)i2 << 20) | (unsigned)s2;
    }
}

// ---------------- combine: out[t] = pbuf[slotA] + pbuf[slotB] ----------------
__global__ void combine_kernel(const unsigned short* __restrict__ pbuf,
                               const unsigned int* __restrict__ slot_of,
                               const int* __restrict__ off, float* __restrict__ out) {
    int t = blockIdx.x, tid = threadIdx.x;
    unsigned int a = slot_of[2 * t], b = slot_of[2 * t + 1];
    size_t ra = (size_t)(off[a >> 20] + (int)(a & 0xFFFFFu));
    size_t rb = (size_t)(off[b >> 20] + (int)(b & 0xFFFFFu));
    const unsigned short* pa = pbuf + ra * H_DIM + tid * 8;
    const unsigned short* pb = pbuf + rb * H_DIM + tid * 8;
    ushort4 a0 = *(const ushort4*)pa, a1 = *(const ushort4*)(pa + 4);
    ushort4 b0 = *(const ushort4*)pb, b1 = *(const ushort4*)(pb + 4);
    float4 r0, r1;
    r0.x = bf2f(a0.x) + bf2f(b0.x); r0.y = bf2f(a0.y) + bf2f(b0.y);
    r0.z = bf2f(a0.z) + bf2f(b0.z); r0.w = bf2f(a0.w) + bf2f(b0.w);
    r1.x = bf2f(a1.x) + bf2f(b1.x); r1.y = bf2f(a1.y) + bf2f(b1.y);
    r1.z = bf2f(a1.z) + bf2f(b1.z); r1.w = bf2f(a1.w) + bf2f(b1.w);
    float* op = out + (size_t)t * H_DIM + tid * 8;
    *(float4*)op = r0;
    *(float4*)(op + 4) = r1;
}

// ---------------- 8-phase 256x256 grouped GEMM (round-3 fused rhythm) ----------------
// Phase = {ds_read | stage-issue | setprio(1) MFMA setprio(0) | [vmcnt] | bar}.
// Blocks with bid >= gemm_grid run an embedded cvt loop instead
// (cvt_mode 1 = flat, 2 = w1 half-1). They time-share CUs with GEMM blocks.
template<int IS_G1>
__global__ __launch_bounds__(512, 2) void moe_gemm_kernel(
    const unsigned short* __restrict__ A_src, const unsigned short* __restrict__ W,
    const int* __restrict__ cnt, const int* __restrict__ off,
    const int* __restrict__ tok_of, const float* __restrict__ wgt_of,
    unsigned short* __restrict__ dst,
    const float* __restrict__ cvt_src, unsigned short* __restrict__ cvt_dst,
    long cvt_n, int gemm_grid, int cvt_blks, int nt_base, int cvt_mode) {
    if ((int)blockIdx.x >= gemm_grid) {
        long i0 = ((long)((int)blockIdx.x - gemm_grid) * blockDim.x + threadIdx.x) * 8;
        long stride = (long)cvt_blks * blockDim.x * 8;
        if (cvt_mode == 2) {
            cvt_w1_half_body<1>(cvt_src, cvt_dst, i0, stride);
        } else {
            for (long i = i0; i < cvt_n; i += stride) cvt8(cvt_src + i, cvt_dst + i);
        }
        return;
    }
    int bx = xcd_swizzle(blockIdx.x, gemm_grid);
    int nt = nt_base + bx / (E_NUM * 32);
    int rr = bx % (E_NUM * 32);
    int e = rr / 32;
    int mt = rr % 32;
    int C = cnt[e];
    if (mt * 256 >= C) return;
    int O = off[e];

    __shared__ __align__(16) char ldsA[2][32768];
    __shared__ __align__(16) char ldsB[2][32768];

    int tid = threadIdx.x;
    int wave = tid >> 6, lane = tid & 63;
    int wr = wave >> 2, wc = wave & 3;

    // ---- staging source pointers (pre-swizzled involution) ----
    const char* aptr[4];
#pragma unroll
    for (int q = 0; q < 4; ++q) {
        int row = q * 64 + wave * 8 + (lane >> 3);
        int cu = (lane & 7) ^ (row & 7);
        int grow = mt * 256 + row; if (grow > C - 1) grow = C - 1;
        size_t arow = IS_G1 ? (size_t)tok_of[e * S_TOK + grow] : (size_t)(O + grow);
        aptr[q] = (const char*)(A_src + arow * 2048 + cu * 8);
    }
    const char* bptr[4];
#pragma unroll
    for (int j = 0; j < 4; ++j) {
        int lrow = j * 64 + wave * 8 + (lane >> 3);
        int cu = (lane & 7) ^ (lrow & 7);
        int np = lrow >> 7, wcg = (lrow >> 5) & 3, rem = lrow & 31;
        int tbrow = wcg * 64 + np * 32 + rem;
        size_t brow;
        if (IS_G1) {
            int jj = tbrow & 63, wq = tbrow >> 6;
            if (jj < 32) brow = (size_t)(nt * 128 + wq * 32 + jj);
            else         brow = (size_t)I_DIM + nt * 128 + wq * 32 + (jj - 32);
            brow += (size_t)e * (2 * I_DIM);
        } else {
            brow = (size_t)e * H_DIM + nt * 256 + tbrow;
        }
        bptr[j] = (const char*)(W + brow * 2048 + cu * 8);
    }

    // ---- swizzled ds_read byte offsets ----
    int aoff[8][2], boff[4][2];
#pragma unroll
    for (int m = 0; m < 8; ++m)
#pragma unroll
        for (int ks = 0; ks < 2; ++ks) {
            int row = wr * 128 + m * 16 + (lane & 15);
            int cu = ks * 4 + (lane >> 4);
            aoff[m][ks] = row * 128 + ((cu ^ (row & 7)) * 16);
        }
#pragma unroll
    for (int n = 0; n < 4; ++n)
#pragma unroll
        for (int ks = 0; ks < 2; ++ks) {
            int lrow = (n >> 1) * 128 + wc * 32 + (n & 1) * 16 + (lane & 15);
            int cu = ks * 4 + (lane >> 4);
            boff[n][ks] = lrow * 128 + ((cu ^ (lrow & 7)) * 16);
        }

    f32x4 acc[8][4];
#pragma unroll
    for (int m = 0; m < 8; ++m)
#pragma unroll
        for (int n = 0; n < 4; ++n)
#pragma unroll
            for (int q = 0; q < 4; ++q) acc[m][n][q] = 0.0f;

    auto gA = [&](int q, int T, int buf) {
        async_copy16(ldsA[buf] + q * 8192 + wave * 1024, aptr[q] + T * 128);
    };
    auto gB = [&](int j, int T, int buf) {
        async_copy16(ldsB[buf] + j * 8192 + wave * 1024, bptr[j] + T * 128);
    };

    // ---- prologue ----
    gA(0, 0, 0); gA(2, 0, 0); gA(1, 0, 0); gA(3, 0, 0);
    gB(0, 0, 0); gB(1, 0, 0);
    gA(0, 1, 1); gA(2, 1, 1); gA(1, 1, 1); gA(3, 1, 1);
    gB(2, 0, 0); gB(3, 0, 0);
    asm volatile("s_waitcnt vmcnt(6)" ::: "memory");
    __builtin_amdgcn_s_barrier();

    bf16x8 ar[8][2], br[2][2];
    int cur = 0;
#pragma unroll 2
    for (int T = 0; T < 32; ++T) {
        int nxt = cur ^ 1;
        int TA = (T + 2 < 32) ? T + 2 : 31;
        int TB = (T + 1 < 32) ? T + 1 : 31;
        // ---- P1 ----
#pragma unroll
        for (int n = 0; n < 2; ++n)
#pragma unroll
            for (int ks = 0; ks < 2; ++ks)
                br[n][ks] = *(const bf16x8*)(ldsB[cur] + boff[n][ks]);
#pragma unroll
        for (int m = 0; m < 4; ++m)
#pragma unroll
            for (int ks = 0; ks < 2; ++ks)
                ar[m][ks] = *(const bf16x8*)(ldsA[cur] + aoff[m][ks]);
        gB(0, TB, nxt); gB(1, TB, nxt);
        __builtin_amdgcn_s_setprio(1);
#pragma unroll
        for (int m = 0; m < 4; ++m)
#pragma unroll
            for (int n = 0; n < 2; ++n) {
                acc[m][n] = MFMA16(ar[m][0], br[n][0], acc[m][n]);
                acc[m][n] = MFMA16(ar[m][1], br[n][1], acc[m][n]);
            }
        __builtin_amdgcn_s_setprio(0);
        __builtin_amdgcn_s_barrier();
        // ---- P2 ----
#pragma unroll
        for (int m = 4; m < 8; ++m)
#pragma unroll
            for (int ks = 0; ks < 2; ++ks)
                ar[m][ks] = *(const bf16x8*)(ldsA[cur] + aoff[m][ks]);
        gA(0, TA, cur); gA(2, TA, cur);
        __builtin_amdgcn_s_setprio(1);
#pragma unroll
        for (int m = 4; m < 8; ++m)
#pragma unroll
            for (int n = 0; n < 2; ++n) {
                acc[m][n] = MFMA16(ar[m][0], br[n][0], acc[m][n]);
                acc[m][n] = MFMA16(ar[m][1], br[n][1], acc[m][n]);
            }
        __builtin_amdgcn_s_setprio(0);
        asm volatile("s_waitcnt vmcnt(4)" ::: "memory");
        __builtin_amdgcn_s_barrier();
        // ---- P3 ----
#pragma unroll
        for (int n = 0; n < 2; ++n)
#pragma unroll
            for (int ks = 0; ks < 2; ++ks)
                br[n][ks] = *(const bf16x8*)(ldsB[cur] + boff[n + 2][ks]);
        gA(1, TA, cur); gA(3, TA, cur);
        __builtin_amdgcn_s_setprio(1);
#pragma unroll
        for (int m = 0; m < 4; ++m)
#pragma unroll
            for (int n = 0; n < 2; ++n) {
                acc[m][n + 2] = MFMA16(ar[m][0], br[n][0], acc[m][n + 2]);
                acc[m][n + 2] = MFMA16(ar[m][1], br[n][1], acc[m][n + 2]);
            }
        __builtin_amdgcn_s_setprio(0);
        __builtin_amdgcn_s_barrier();
        // ---- P4 ----
        gB(2, TB, nxt); gB(3, TB, nxt);
        __builtin_amdgcn_s_setprio(1);
#pragma unroll
        for (int m = 4; m < 8; ++m)
#pragma unroll
            for (int n = 0; n < 2; ++n) {
                acc[m][n + 2] = MFMA16(ar[m][0], br[n][0], acc[m][n + 2]);
                acc[m][n + 2] = MFMA16(ar[m][1], br[n][1], acc[m][n + 2]);
            }
        __builtin_amdgcn_s_setprio(0);
        asm volatile("s_waitcnt vmcnt(6)" ::: "memory");
        __builtin_amdgcn_s_barrier();
        cur = nxt;
    }

    // ---- epilogue ----
    if (IS_G1) {
#pragma unroll
        for (int m = 0; m < 8; ++m)
#pragma unroll
            for (int q = 0; q < 4; ++q) {
                int row = mt * 256 + wr * 128 + m * 16 + (lane >> 4) * 4 + q;
                if (row < C) {
                    float wgt = wgt_of[e * S_TOK + row];
                    unsigned short* hp = dst + (size_t)(O + row) * I_DIM +
                                         nt * 128 + wc * 32 + (lane & 15);
#pragma unroll
                    for (int n = 0; n < 2; ++n) {
                        float g = acc[m][n][q];
                        float u = acc[m][n + 2][q];
                        float hv = (g / (1.0f + __expf(-g))) * u * wgt;
                        hp[n * 16] = f2bf(hv);
                    }
                }
            }
    } else {
#pragma unroll
        for (int m = 0; m < 8; ++m)
#pragma unroll
            for (int q = 0; q < 4; ++q) {
                int row = mt * 256 + wr * 128 + m * 16 + (lane >> 4) * 4 + q;
                if (row < C) {
                    unsigned short* pp = dst + (size_t)(O + row) * H_DIM +
                                         nt * 256 + wc * 64 + (lane & 15);
#pragma unroll
                    for (int n = 0; n < 4; ++n)
                        pp[n * 16] = f2bf(acc[m][n][q]);
                }
            }
    }
}

extern "C" void kernel_launch(void* const* d_in, const int* in_sizes, int n_in,
                              void* d_out, int out_size, void* d_ws, size_t ws_size,
                              hipStream_t stream) {
    const float* hs = (const float*)d_in[0];
    const float* wg = (const float*)d_in[1];
    const float* w1 = (const float*)d_in[2];
    const float* w2 = (const float*)d_in[3];

    float* out = (float*)d_out;
    float* logits = out + (size_t)S_TOK * H_DIM;

    char* ws = (char*)d_ws;
    int* cnt = (int*)ws;
    int* off = (int*)(ws + 256);
    int* tok_of = (int*)(ws + 512);
    float* wgt_of = (float*)(ws + 512 + (size_t)E_NUM * S_TOK * 4);
    unsigned int* slot_of = (unsigned int*)(ws + 512 + (size_t)E_NUM * S_TOK * 8);
    unsigned int* tchoice = (unsigned int*)(ws + 512 + (size_t)E_NUM * S_TOK * 8 + (size_t)S_TOK * 8);
    float* twgt = (float*)(ws + 512 + (size_t)E_NUM * S_TOK * 8 + (size_t)S_TOK * 12);
    size_t o = 512 + (size_t)E_NUM * S_TOK * 8 + (size_t)S_TOK * 16;
    o = (o + 4095) & ~(size_t)4095;
    unsigned short* hsb = (unsigned short*)(ws + o);  o += (size_t)S_TOK * H_DIM * 2;             // 32 MiB
    unsigned short* wxb = (unsigned short*)(ws + o);  o += (size_t)E_NUM * 2 * I_DIM * H_DIM * 2; // 128 MiB (w1)
    unsigned short* hbuf = (unsigned short*)(ws + o); o += (size_t)S_TOK * 2 * I_DIM * 2;         // 64 MiB
    size_t o_w2 = o;                                  // separate 64 MiB w2 region (fused mode)
    size_t need_fused = o_w2 + (size_t)E_NUM * H_DIM * I_DIM * 2;
    bool fused = (ws_size >= need_fused);

    const long W1_N = (long)E_NUM * 2 * I_DIM * H_DIM;
    const long W2_N = (long)E_NUM * H_DIM * I_DIM;
    const int G1H_GRID = E_NUM * 32 * 8;  // 2048 (half of gemm1's nt range)
    const int G2_GRID = E_NUM * 32 * 8;   // 2048
    const int CVT_BLKS = 1024;

    router_kernel<<<S_TOK, 256, 0, stream>>>(hs, wg, logits, tchoice, twgt, hsb);
    scan_kernel<<<1, 1024, 0, stream>>>(tchoice, twgt, cnt, off, tok_of, wgt_of, slot_of);

    if (fused) {
        unsigned short* w2b = (unsigned short*)(ws + o_w2);
        unsigned short* pbuf = wxb;  // w1 dead after gemm1b
        cvt_w1_half_kernel<0><<<4096, 256, 0, stream>>>(w1, wxb);
        moe_gemm_kernel<1><<<G1H_GRID + CVT_BLKS, 512, 0, stream>>>(
            hsb, wxb, cnt, off, tok_of, wgt_of, hbuf,
            w1, wxb, 0, G1H_GRID, CVT_BLKS, 0, 2);
        moe_gemm_kernel<1><<<G1H_GRID + CVT_BLKS, 512, 0, stream>>>(
            hsb, wxb, cnt, off, tok_of, wgt_of, hbuf,
            w2, w2b, W2_N, G1H_GRID, CVT_BLKS, 8, 1);
        moe_gemm_kernel<0><<<G2_GRID, 512, 0, stream>>>(
            hbuf, w2b, cnt, off, tok_of, wgt_of, pbuf,
            nullptr, nullptr, 0, G2_GRID, 0, 0, 0);
        combine_kernel<<<S_TOK, 256, 0, stream>>>(pbuf, slot_of, off, out);
    } else {
        unsigned short* w2b = wxb;
        unsigned short* pbuf = wxb + (size_t)E_NUM * H_DIM * I_DIM;
        cvt_kernel<<<4096, 256, 0, stream>>>(w1, wxb, W1_N);
        moe_gemm_kernel<1><<<E_NUM * 32 * 16, 512, 0, stream>>>(
            hsb, wxb, cnt, off, tok_of, wgt_of, hbuf,
            nullptr, nullptr, 0, E_NUM * 32 * 16, 0, 0, 0);
        cvt_kernel<<<4096, 256, 0, stream>>>(w2, w2b, W2_N);
        moe_gemm_kernel<0><<<G2_GRID, 512, 0, stream>>>(
            hbuf, w2b, cnt, off, tok_of, wgt_of, pbuf,
            nullptr, nullptr, 0, G2_GRID, 0, 0, 0);
        combine_kernel<<<S_TOK, 256, 0, stream>>>(pbuf, slot_of, off, out);
    }
}